// Round 16
// baseline (736.822 us; speedup 1.0000x reference)
//
#include <hip/hip_runtime.h>
#include <hip/hip_bf16.h>
#include <hip/hip_cooperative_groups.h>

namespace cg = cooperative_groups;

#define N_NODES 8192
#define D_IN 32
#define N3 6144
#define N2 4096
#define N1 2048
#define N0 1024
#define NE 16384
#define KZ 4                     // grid-level k-slices
#define KRANGE (N_NODES / KZ)    // 2048 k per block
#define KWAVE (KRANGE / 4)       // 512 k per wave (4 waves)
#define NSTAGE (KWAVE / 64)      // 8 stages of 64 k

using f32x4 = __attribute__((ext_vector_type(4))) float;
using s16x8 = __attribute__((ext_vector_type(8))) short;

__device__ __forceinline__ short f2bf(float f) {
    union { __hip_bfloat16 b; short s; } u;
    u.b = __float2bfloat16(f);
    return u.s;
}
__device__ __forceinline__ float b2f(short s) {
    unsigned int u = ((unsigned int)(unsigned short)s) << 16;
    float f;
    __builtin_memcpy(&f, &u, 4);
    return f;
}
__device__ __forceinline__ void gload16(const float* g, float* l) {
    __builtin_amdgcn_global_load_lds(
        (const __attribute__((address_space(1))) void*)g,
        (__attribute__((address_space(3))) void*)l, 16, 0, 0);
}

// ---------------------------------------------------------------------------
// prep (r13/r15-verified, verbatim)
// ---------------------------------------------------------------------------
__global__ __launch_bounds__(1024) void prep_kernel(
    const void* __restrict__ nraw, const float* __restrict__ x,
    const float* __restrict__ tau_p, int* __restrict__ n32,
    int* __restrict__ cntA, int* __restrict__ cntB,
    int* __restrict__ listA, int* __restrict__ listB, int* __restrict__ listC,
    int* __restrict__ flags,
    unsigned short* __restrict__ xh, unsigned short* __restrict__ xl,
    float4* __restrict__ zbase, int zn4) {
    __shared__ int lcnt[N_NODES];
    __shared__ float tile[128][33];
    __shared__ int lnum, lfl;
    const int b = blockIdx.x, t = threadIdx.x;
    const int* ni = (const int*)nraw;
    const long long* nl = (const long long*)nraw;

    if (b == 0) {
        bool n64 = true;
#pragma unroll
        for (int j = 0; j < 8; ++j) {
            long long a = nl[j];
            if (a < 0 || a >= N_NODES) n64 = false;
        }
        if (t == 0) { lnum = 0; lfl = 0; }
        for (int i = t; i < N_NODES; i += 1024) lcnt[i] = 0;
        __syncthreads();
        for (int j = t; j < N3; j += 1024) {
            long long v = n64 ? nl[j] : (long long)ni[j];
            if (v < 0 || v >= N_NODES) { atomicOr(&lfl, 2); v = 0; }
            if (j < N1) n32[j] = (int)v;
            atomicAdd(&lcnt[(int)v], 1);
        }
        __syncthreads();
        for (int c = t; c < N_NODES; c += 1024) {
            int cv = lcnt[c];
            cntA[c] = cv;
            if (cv) listA[atomicAdd(&lnum, 1)] = c;
        }
        __syncthreads();
        if (t == 0) { flags[2] = lnum; lnum = 0; }
        __syncthreads();
        for (int i = t; i < N_NODES; i += 1024) lcnt[i] = 0;
        __syncthreads();
        for (int j = t; j < N2; j += 1024) {
            long long v = n64 ? nl[j] : (long long)ni[j];
            v = (v < 0 || v >= N_NODES) ? 0 : v;
            atomicAdd(&lcnt[(int)v], 1);
        }
        __syncthreads();
        for (int c = t; c < N_NODES; c += 1024) {
            int cv = lcnt[c];
            cntB[c] = cv;
            if (cv) listB[atomicAdd(&lnum, 1)] = c;
        }
        __syncthreads();
        if (t == 0) { flags[3] = lnum; lnum = 0; }
        __syncthreads();
        for (int i = t; i < N_NODES; i += 1024) lcnt[i] = 0;
        __syncthreads();
        for (int j = t; j < N1; j += 1024) {
            long long v = n64 ? nl[j] : (long long)ni[j];
            v = (v < 0 || v >= N_NODES) ? 0 : v;
            atomicAdd(&lcnt[(int)v], 1);
        }
        __syncthreads();
        for (int c = t; c < N_NODES; c += 1024) {
            if (lcnt[c]) listC[atomicAdd(&lnum, 1)] = c;
        }
        __syncthreads();
        if (t == 0) {
            flags[4] = lnum;
            int f = lfl;
            if (fabsf(tau_p[0] - 0.1f) > 1e-6f) f |= 32;
            flags[0] = f;
        }
    } else {
        if (b <= 64) {
            const int c0 = (b - 1) * 128;
            const int d = t & 31, cc = t >> 5;
#pragma unroll
            for (int i = 0; i < 4; ++i)
                tile[cc + 32 * i][d] = x[(size_t)(c0 + cc + 32 * i) * D_IN + d];
            __syncthreads();
#pragma unroll
            for (int i = 0; i < 4; ++i) {
                int idx = t + 1024 * i;
                int dd = idx >> 7;
                int jj = idx & 127;
                float v = tile[jj][dd];
                short h = f2bf(v);
                xh[(size_t)dd * N_NODES + c0 + jj] = (unsigned short)h;
                xl[(size_t)dd * N_NODES + c0 + jj] = (unsigned short)f2bf(v - b2f(h));
            }
        }
        float4 zz = {0.f, 0.f, 0.f, 0.f};
        for (int i = (b - 1) * 1024 + t; i < zn4; i += 259 * 1024) zbase[i] = zz;
    }
}

// ---------------------------------------------------------------------------
// mm tile body (r15-verified math; tileA doubles as the reduction buffer
// after the k-loop — extra __syncthreads protect the alias and unit reuse)
// ---------------------------------------------------------------------------
template <int MODE>
__device__ __forceinline__ void mm_tile_body(
    const float* __restrict__ Km0, const float* __restrict__ Km1,
    const unsigned short* __restrict__ Bhi, const unsigned short* __restrict__ Blo,
    const int* __restrict__ list, int nrows, int tix, int y, int z,
    const float* __restrict__ zpad, float* __restrict__ outf,
    float* tileA, int* rows_s) {
    constexpr int NF = (MODE == 2) ? 4 : 2;
    constexpr int NCTOT = (MODE == 0) ? 32 : ((MODE == 1) ? 64 : 128);
    const int c0 = tix * 16;
    const int tid = threadIdx.x;
    const int lane = tid & 63;
    const int wid = tid >> 6;
    const int row = lane & 15;
    const int kg = lane >> 4;

    __syncthreads();     // previous unit's readers of rows_s/tileA done
    if (tid < 16) rows_s[tid] = (c0 + tid < nrows) ? list[c0 + tid] : -1;
    __syncthreads();

    const float* Km = (MODE == 0) ? Km0 : (y ? Km1 : Km0);
    const int zoff = (MODE == 0) ? 0 : y * ((MODE == 1) ? 32 : 64);

    const unsigned short* bph[NF];
    const unsigned short* bpl[NF];
    const int kwb = z * KRANGE + wid * KWAVE;
#pragma unroll
    for (int n = 0; n < NF; ++n) {
        size_t boffs = (size_t)(n * 16 + row) * N_NODES + kwb + kg * 8;
        bph[n] = Bhi + boffs;
        bpl[n] = Blo + boffs;
    }

    f32x4 acc[NF];
#pragma unroll
    for (int n = 0; n < NF; ++n) acc[n] = (f32x4){0.f, 0.f, 0.f, 0.f};

    float* twave = tileA + wid * 2048;    // [2][1024] per wave
    const int srow = lane >> 4;
    const int schk = lane & 15;
#define ISSUE(buf, kofs)                                                       \
    {                                                                          \
        _Pragma("unroll") for (int i = 0; i < 4; ++i) {                        \
            int r = i * 4 + srow;                                              \
            int crw = rows_s[r];                                               \
            int sc = schk ^ (r & 15);                                          \
            const float* gp = (crw >= 0)                                       \
                                  ? Km + (size_t)crw * N_NODES + (kofs) + sc * 4 \
                                  : zpad;                                      \
            gload16(gp, twave + (buf) * 1024 + i * 256);                       \
        }                                                                      \
    }

    ISSUE(0, kwb);
    for (int st = 0; st < NSTAGE; ++st) {
        const int buf = st & 1;
        if (st + 1 < NSTAGE) {
            ISSUE(buf ^ 1, kwb + (st + 1) * 64);
            asm volatile("s_waitcnt vmcnt(4)" ::: "memory");
        } else {
            asm volatile("s_waitcnt vmcnt(0)" ::: "memory");
        }
        __builtin_amdgcn_sched_barrier(0);
        const float* tb = twave + buf * 1024;
#pragma unroll
        for (int ks = 0; ks < 64; ks += 32) {
            int c0i = (kg * 8 + ks) >> 2;
            float4 a0 = *(const float4*)&tb[row * 64 + ((c0i ^ (row & 15)) << 2)];
            float4 a1 = *(const float4*)&tb[row * 64 + (((c0i + 1) ^ (row & 15)) << 2)];
            float av[8] = {a0.x, a0.y, a0.z, a0.w, a1.x, a1.y, a1.z, a1.w};
            s16x8 ah, al;
#pragma unroll
            for (int i = 0; i < 8; ++i) {
                short h = f2bf(av[i]);
                ah[i] = h;
                al[i] = f2bf(av[i] - b2f(h));
            }
            const int bo = st * 64 + ks;
#pragma unroll
            for (int n = 0; n < NF; ++n) {
                s16x8 bh = *(const s16x8*)(bph[n] + bo);
                s16x8 bl = *(const s16x8*)(bpl[n] + bo);
                acc[n] = __builtin_amdgcn_mfma_f32_16x16x32_bf16(al, bh, acc[n], 0, 0, 0);
                acc[n] = __builtin_amdgcn_mfma_f32_16x16x32_bf16(ah, bl, acc[n], 0, 0, 0);
                acc[n] = __builtin_amdgcn_mfma_f32_16x16x32_bf16(ah, bh, acc[n], 0, 0, 0);
            }
        }
        __builtin_amdgcn_sched_barrier(0);
    }
#undef ISSUE

    // reduction buffer aliases tileA (dead after last stage for ALL waves)
    __syncthreads();
    float* redb = tileA;
#pragma unroll
    for (int n = 0; n < NF; ++n)
#pragma unroll
        for (int r = 0; r < 4; ++r)
            redb[wid * (256 * NF) + (kg * 4 + r) * (16 * NF) + (n * 16 + row)] =
                acc[n][r];
    __syncthreads();

    for (int e = tid; e < 256 * NF; e += 256) {
        float s = redb[e] + redb[256 * NF + e] + redb[2 * 256 * NF + e] +
                  redb[3 * 256 * NF + e];
        int orow = e / (16 * NF);
        int ocol = e % (16 * NF);
        int cc = rows_s[orow];
        if (cc >= 0) atomicAdd(&outf[(size_t)cc * NCTOT + zoff + ocol], s);
    }
}

// epilogue element ops (r15-verified math)
__device__ __forceinline__ void ep0_elem(int idx, const float* x, const float* pA,
                                         const float* tau_p, const int* cntA,
                                         unsigned short* uAh, unsigned short* uAl) {
    int d = idx >> 13, c = idx & (N_NODES - 1);
    float u = (float)cntA[c] * (x[(size_t)c * D_IN + d] - tau_p[0] * pA[(size_t)c * 32 + d]);
    short h = f2bf(u);
    uAh[idx] = (unsigned short)h;
    uAl[idx] = (unsigned short)f2bf(u - b2f(h));
}
__device__ __forceinline__ void ep1_elem(int idx, const float* g1, const int* cntB,
                                         unsigned short* uBh, unsigned short* uBl) {
    int d = idx >> 13, c = idx & (N_NODES - 1);
    float u = (float)cntB[c] * g1[(size_t)c * 64 + d];
    short h = f2bf(u);
    uBh[idx] = (unsigned short)h;
    uBl[idx] = (unsigned short)f2bf(u - b2f(h));
}

// head body (r15-verified), b = output block index
__device__ __forceinline__ void head_body(
    const float* __restrict__ g1, const float* __restrict__ g2,
    const int* __restrict__ n32, const void* __restrict__ eraw,
    const float* __restrict__ Wself, const float* __restrict__ Wneigh,
    const float* __restrict__ bconv, const float* __restrict__ W1,
    const float* __restrict__ b1, const float* __restrict__ W2,
    const float* __restrict__ b2, const int* __restrict__ flags,
    float* __restrict__ out, int b, float* zs, float* za, float* hc, float* hm,
    int* csrc) {
    int t = threadIdx.x;
    const int* ei = (const int*)eraw;
    const long long* el = (const long long*)eraw;
    if (t < 16) {
        bool e64 = true;
#pragma unroll
        for (int j = 0; j < 8; ++j) {
            long long a = el[j];
            if (a < 0 || a >= N1) e64 = false;
        }
        long long sv = e64 ? el[b * 16 + t] : (long long)ei[b * 16 + t];
        int si = (sv < 0 || sv >= N1) ? 0 : (int)sv;
        csrc[t] = n32[si];
    }
    __syncthreads();
    if (t < 192) {
        int cb = n32[b];
        zs[t] = (t < 64) ? g1[(size_t)cb * 64 + t] : g2[(size_t)cb * 128 + (t - 64)];
        float s = 0.f;
#pragma unroll
        for (int e = 0; e < 16; ++e) {
            int c = csrc[e];
            s += (t < 64) ? g1[(size_t)c * 64 + t] : g2[(size_t)c * 128 + (t - 64)];
        }
        za[t] = s * (1.0f / 16.0f);
    }
    __syncthreads();
    if (t < 128) {
        float s = bconv[t];
        for (int d = 0; d < 192; ++d)
            s += zs[d] * Wself[d * 128 + t] + za[d] * Wneigh[d * 128 + t];
        hc[t] = s;
    }
    __syncthreads();
    if (t < 64) {
        float s = b1[t];
        for (int h = 0; h < 128; ++h) s += hc[h] * W1[h * 64 + t];
        hm[t] = fmaxf(s, 0.0f);
    }
    __syncthreads();
    if (t < 32) {
        float s = b2[t];
        for (int j = 0; j < 64; ++j) s += hm[j] * W2[j * 32 + t];
        out[(size_t)b * 32 + t] = s;
    }
    __syncthreads();
    if (b == 0 && t == 0) {
        int f = flags[0];
        if (f) out[0] = 100000.0f * (float)f;
    }
}

// ---------------------------------------------------------------------------
// COOPERATIVE fused kernel: mm0 | ep0 | mm1 | ep1 | mm2 | head, grid.sync()
// between phases. LDS ~34.6 KB -> 4 blocks/CU co-residency.
// ---------------------------------------------------------------------------
struct FA {
    const float *L, *K0, *K1, *x, *tau;
    const int *cntA, *cntB, *listA, *listB, *listC, *flags, *n32;
    const void* eraw;
    const unsigned short *xh, *xl;
    unsigned short *uAh, *uAl, *uBh, *uBl;
    const float *Wself, *Wneigh, *bconv, *W1, *b1, *W2, *b2, *zpad;
    float *pA, *g1, *g2, *out;
};

__global__ __launch_bounds__(256, 4) void fused_kernel(FA a) {
    cg::grid_group grid = cg::this_grid();
    __shared__ float tileA[4 * 2 * 1024];     // 32 KB (also reduction buffer)
    __shared__ int rows_s[16];
    __shared__ float zs[192], za[192], hc[128], hm[64];
    __shared__ int csrc[16];
    const int bid = blockIdx.x, nb = gridDim.x, tid = threadIdx.x;

    const int nA = a.flags[2], nB = a.flags[3], nC = a.flags[4];
    const int ntA = (nA + 15) >> 4, ntB = (nB + 15) >> 4, ntC = (nC + 15) >> 4;

    // mm0: pA += L[rows, kslice] @ x
    for (int w = bid; w < ntA * KZ; w += nb)
        mm_tile_body<0>(a.L, a.L, a.xh, a.xl, a.listA, nA, w % ntA, 0, w / ntA,
                        a.zpad, a.pA, tileA, rows_s);
    grid.sync();
    // ep0
    for (int idx = bid * 256 + tid; idx < N_NODES * 32; idx += nb * 256)
        ep0_elem(idx, a.x, a.pA, a.tau, a.cntA, a.uAh, a.uAl);
    grid.sync();
    // mm1: g1 += [K0|K1][rows, kslice] @ uA
    for (int w = bid; w < ntB * 2 * KZ; w += nb) {
        int tix = w % ntB, rem = w / ntB;
        mm_tile_body<1>(a.K0, a.K1, a.uAh, a.uAl, a.listB, nB, tix, rem & 1,
                        rem >> 1, a.zpad, a.g1, tileA, rows_s);
    }
    grid.sync();
    // ep1
    for (int idx = bid * 256 + tid; idx < N_NODES * 64; idx += nb * 256)
        ep1_elem(idx, a.g1, a.cntB, a.uBh, a.uBl);
    grid.sync();
    // mm2: g2 += [K0|K1][rows, kslice] @ uB (NF=4)
    for (int w = bid; w < ntC * 2 * KZ; w += nb) {
        int tix = w % ntC, rem = w / ntC;
        mm_tile_body<2>(a.K0, a.K1, a.uBh, a.uBl, a.listC, nC, tix, rem & 1,
                        rem >> 1, a.zpad, a.g2, tileA, rows_s);
    }
    grid.sync();
    // head + canary
    for (int hb = bid; hb < N0; hb += nb)
        head_body(a.g1, a.g2, a.n32, a.eraw, a.Wself, a.Wneigh, a.bconv, a.W1,
                  a.b1, a.W2, a.b2, a.flags, a.out, hb, zs, za, hc, hm, csrc);
}

// ---------------------------------------------------------------------------
// Fallback standalone kernels (r15-verified launch structure)
// ---------------------------------------------------------------------------
template <int MODE>
__global__ __launch_bounds__(256) void rows_mmg(
    const float* __restrict__ Km0, const float* __restrict__ Km1,
    const unsigned short* __restrict__ Bhi, const unsigned short* __restrict__ Blo,
    const int* __restrict__ list, const int* __restrict__ nptr, int nidx,
    const float* __restrict__ zpad, float* __restrict__ outf) {
    __shared__ float tileA[4 * 2 * 1024];
    __shared__ int rows_s[16];
    int nrows = nptr[nidx];
    if ((int)blockIdx.x * 16 >= nrows) return;
    mm_tile_body<MODE>(Km0, Km1, Bhi, Blo, list, nrows, blockIdx.x, blockIdx.y,
                       blockIdx.z, zpad, outf, tileA, rows_s);
}

__global__ void ep0_kernel(const float* __restrict__ x, const float* __restrict__ pA,
                           const float* __restrict__ tau_p, const int* __restrict__ cntA,
                           unsigned short* __restrict__ uAh, unsigned short* __restrict__ uAl) {
    int idx = blockIdx.x * 256 + threadIdx.x;
    if (idx < N_NODES * 32) ep0_elem(idx, x, pA, tau_p, cntA, uAh, uAl);
}
__global__ void ep1_kernel(const float* __restrict__ g1, const int* __restrict__ cntB,
                           unsigned short* __restrict__ uBh, unsigned short* __restrict__ uBl) {
    int idx = blockIdx.x * 256 + threadIdx.x;
    if (idx < N_NODES * 64) ep1_elem(idx, g1, cntB, uBh, uBl);
}
__global__ void head_kernel(const float* __restrict__ g1, const float* __restrict__ g2,
                            const int* __restrict__ n32, const void* __restrict__ eraw,
                            const float* __restrict__ Wself, const float* __restrict__ Wneigh,
                            const float* __restrict__ bconv, const float* __restrict__ W1,
                            const float* __restrict__ b1, const float* __restrict__ W2,
                            const float* __restrict__ b2, const int* __restrict__ flags,
                            float* __restrict__ out) {
    __shared__ float zs[192], za[192], hc[128], hm[64];
    __shared__ int csrc[16];
    head_body(g1, g2, n32, eraw, Wself, Wneigh, bconv, W1, b1, W2, b2, flags, out,
              blockIdx.x, zs, za, hc, hm, csrc);
}

__global__ void ws_fail_kernel(float* out) {
    if (threadIdx.x == 0 && blockIdx.x == 0) out[0] = 100000.0f;
}

// ---------------------------------------------------------------------------
extern "C" void kernel_launch(void* const* d_in, const int* in_sizes, int n_in,
                              void* d_out, int out_size, void* d_ws, size_t ws_size,
                              hipStream_t stream) {
    const float* x      = (const float*)d_in[0];
    const float* tau    = (const float*)d_in[1];
    const float* L      = (const float*)d_in[2];
    const float* K0     = (const float*)d_in[3];
    const float* K1     = (const float*)d_in[4];
    const float* Wself  = (const float*)d_in[5];
    const float* Wneigh = (const float*)d_in[6];
    const float* bconv  = (const float*)d_in[7];
    const float* W1     = (const float*)d_in[8];
    const float* b1     = (const float*)d_in[9];
    const float* W2     = (const float*)d_in[10];
    const float* b2     = (const float*)d_in[11];
    float* out = (float*)d_out;

    char* ws = (char*)d_ws;
    size_t off = 0;
    int* flags = (int*)(ws + off); off += 256;
    int* cntA  = (int*)(ws + off); off += 32768;
    int* cntB  = (int*)(ws + off); off += 32768;
    int* n32   = (int*)(ws + off); off += 8192;
    int* listA = (int*)(ws + off); off += 32768;
    int* listB = (int*)(ws + off); off += 32768;
    int* listC = (int*)(ws + off); off += 32768;
    float* zpad = (float*)(ws + off); off += 1024;
    float* pA = (float*)(ws + off); off += (size_t)N_NODES * 32 * 4;
    float* g1 = (float*)(ws + off); off += (size_t)N_NODES * 64 * 4;
    float* g2 = (float*)(ws + off); off += (size_t)N_NODES * 128 * 4;
    unsigned short* xh  = (unsigned short*)(ws + off); off += (size_t)32 * N_NODES * 2;
    unsigned short* xl  = (unsigned short*)(ws + off); off += (size_t)32 * N_NODES * 2;
    unsigned short* uAh = (unsigned short*)(ws + off); off += (size_t)32 * N_NODES * 2;
    unsigned short* uAl = (unsigned short*)(ws + off); off += (size_t)32 * N_NODES * 2;
    unsigned short* uBh = (unsigned short*)(ws + off); off += (size_t)64 * N_NODES * 2;
    unsigned short* uBl = (unsigned short*)(ws + off); off += (size_t)64 * N_NODES * 2;
    const size_t needed = off;

    if (ws_size < needed || n_in != 14 || out_size != N0 * 32) {
        ws_fail_kernel<<<1, 64, 0, stream>>>(out);
        return;
    }

    const int zn4 = (int)((1024 + (size_t)(32 + 64 + 128) * N_NODES * 4) / 16);

    // 1) prep
    prep_kernel<<<260, 1024, 0, stream>>>(d_in[12], x, tau, n32, cntA, cntB, listA,
                                          listB, listC, flags, xh, xl, (float4*)zpad,
                                          zn4);

    // 2) cooperative fused chain, with r15 fallback
    FA fa;
    fa.L = L; fa.K0 = K0; fa.K1 = K1; fa.x = x; fa.tau = tau;
    fa.cntA = cntA; fa.cntB = cntB;
    fa.listA = listA; fa.listB = listB; fa.listC = listC;
    fa.flags = flags; fa.n32 = n32; fa.eraw = d_in[13];
    fa.xh = xh; fa.xl = xl;
    fa.uAh = uAh; fa.uAl = uAl; fa.uBh = uBh; fa.uBl = uBl;
    fa.Wself = Wself; fa.Wneigh = Wneigh; fa.bconv = bconv;
    fa.W1 = W1; fa.b1 = b1; fa.W2 = W2; fa.b2 = b2;
    fa.zpad = zpad; fa.pA = pA; fa.g1 = g1; fa.g2 = g2; fa.out = out;

    int maxAct = 0;
    hipError_t qe = hipOccupancyMaxActiveBlocksPerMultiprocessor(&maxAct,
                                                                 fused_kernel, 256, 0);
    bool coop_ok = false;
    if (qe == hipSuccess && maxAct > 0) {
        int gridsz = maxAct * 256;
        if (gridsz > 1024) gridsz = 1024;
        void* args[] = {(void*)&fa};
        coop_ok = (hipLaunchCooperativeKernel((const void*)fused_kernel,
                                              dim3(gridsz), dim3(256), args, 0,
                                              stream) == hipSuccess);
    }
    if (!coop_ok) {
        rows_mmg<0><<<dim3(384, 1, KZ), 256, 0, stream>>>(L, L, xh, xl, listA,
                                                          flags + 2, 0, zpad, pA);
        ep0_kernel<<<1024, 256, 0, stream>>>(x, pA, tau, cntA, uAh, uAl);
        rows_mmg<1><<<dim3(256, 2, KZ), 256, 0, stream>>>(K0, K1, uAh, uAl, listB,
                                                          flags + 2, 1, zpad, g1);
        ep1_kernel<<<2048, 256, 0, stream>>>(g1, cntB, uBh, uBl);
        rows_mmg<2><<<dim3(128, 2, KZ), 256, 0, stream>>>(K0, K1, uBh, uBl, listC,
                                                          flags + 2, 2, zpad, g2);
        head_kernel<<<1024, 256, 0, stream>>>(g1, g2, n32, d_in[13], Wself, Wneigh,
                                              bconv, W1, b1, W2, b2, flags, out);
    }
}

// Round 17
// 241.087 us; speedup vs baseline: 3.0562x; 3.0562x over previous
//
#include <hip/hip_runtime.h>
#include <hip/hip_bf16.h>

#define N_NODES 8192
#define D_IN 32
#define N3 6144
#define N2 4096
#define N1 2048
#define N0 1024
#define NE 16384
#define KZ 4                     // grid-level k-slices
#define KRANGE (N_NODES / KZ)    // 2048 k per block
#define KWAVE (KRANGE / 4)       // 512 k per wave (4 waves)
#define NSTAGE (KWAVE / 64)      // 8 stages of 64 k

using f32x4 = __attribute__((ext_vector_type(4))) float;
using s16x8 = __attribute__((ext_vector_type(8))) short;

__device__ __forceinline__ short f2bf(float f) {
    union { __hip_bfloat16 b; short s; } u;
    u.b = __float2bfloat16(f);
    return u.s;
}
__device__ __forceinline__ float b2f(short s) {
    unsigned int u = ((unsigned int)(unsigned short)s) << 16;
    float f;
    __builtin_memcpy(&f, &u, 4);
    return f;
}
__device__ __forceinline__ void gload16(const float* g, float* l) {
    __builtin_amdgcn_global_load_lds(
        (const __attribute__((address_space(1))) void*)g,
        (__attribute__((address_space(3))) void*)l, 16, 0, 0);
}

// ---------------------------------------------------------------------------
// prep (r13/r15-verified, verbatim)
// ---------------------------------------------------------------------------
__global__ __launch_bounds__(1024) void prep_kernel(
    const void* __restrict__ nraw, const float* __restrict__ x,
    const float* __restrict__ tau_p, int* __restrict__ n32,
    int* __restrict__ cntA, int* __restrict__ cntB,
    int* __restrict__ listA, int* __restrict__ listB, int* __restrict__ listC,
    int* __restrict__ flags,
    unsigned short* __restrict__ xh, unsigned short* __restrict__ xl,
    float4* __restrict__ zbase, int zn4) {
    __shared__ int lcnt[N_NODES];
    __shared__ float tile[128][33];
    __shared__ int lnum, lfl;
    const int b = blockIdx.x, t = threadIdx.x;
    const int* ni = (const int*)nraw;
    const long long* nl = (const long long*)nraw;

    if (b == 0) {
        bool n64 = true;
#pragma unroll
        for (int j = 0; j < 8; ++j) {
            long long a = nl[j];
            if (a < 0 || a >= N_NODES) n64 = false;
        }
        if (t == 0) { lnum = 0; lfl = 0; }
        for (int i = t; i < N_NODES; i += 1024) lcnt[i] = 0;
        __syncthreads();
        for (int j = t; j < N3; j += 1024) {
            long long v = n64 ? nl[j] : (long long)ni[j];
            if (v < 0 || v >= N_NODES) { atomicOr(&lfl, 2); v = 0; }
            if (j < N1) n32[j] = (int)v;
            atomicAdd(&lcnt[(int)v], 1);
        }
        __syncthreads();
        for (int c = t; c < N_NODES; c += 1024) {
            int cv = lcnt[c];
            cntA[c] = cv;
            if (cv) listA[atomicAdd(&lnum, 1)] = c;
        }
        __syncthreads();
        if (t == 0) { flags[2] = lnum; lnum = 0; }
        __syncthreads();
        for (int i = t; i < N_NODES; i += 1024) lcnt[i] = 0;
        __syncthreads();
        for (int j = t; j < N2; j += 1024) {
            long long v = n64 ? nl[j] : (long long)ni[j];
            v = (v < 0 || v >= N_NODES) ? 0 : v;
            atomicAdd(&lcnt[(int)v], 1);
        }
        __syncthreads();
        for (int c = t; c < N_NODES; c += 1024) {
            int cv = lcnt[c];
            cntB[c] = cv;
            if (cv) listB[atomicAdd(&lnum, 1)] = c;
        }
        __syncthreads();
        if (t == 0) { flags[3] = lnum; lnum = 0; }
        __syncthreads();
        for (int i = t; i < N_NODES; i += 1024) lcnt[i] = 0;
        __syncthreads();
        for (int j = t; j < N1; j += 1024) {
            long long v = n64 ? nl[j] : (long long)ni[j];
            v = (v < 0 || v >= N_NODES) ? 0 : v;
            atomicAdd(&lcnt[(int)v], 1);
        }
        __syncthreads();
        for (int c = t; c < N_NODES; c += 1024) {
            if (lcnt[c]) listC[atomicAdd(&lnum, 1)] = c;
        }
        __syncthreads();
        if (t == 0) {
            flags[4] = lnum;
            int f = lfl;
            if (fabsf(tau_p[0] - 0.1f) > 1e-6f) f |= 32;
            flags[0] = f;
        }
    } else {
        if (b <= 64) {
            const int c0 = (b - 1) * 128;
            const int d = t & 31, cc = t >> 5;
#pragma unroll
            for (int i = 0; i < 4; ++i)
                tile[cc + 32 * i][d] = x[(size_t)(c0 + cc + 32 * i) * D_IN + d];
            __syncthreads();
#pragma unroll
            for (int i = 0; i < 4; ++i) {
                int idx = t + 1024 * i;
                int dd = idx >> 7;
                int jj = idx & 127;
                float v = tile[jj][dd];
                short h = f2bf(v);
                xh[(size_t)dd * N_NODES + c0 + jj] = (unsigned short)h;
                xl[(size_t)dd * N_NODES + c0 + jj] = (unsigned short)f2bf(v - b2f(h));
            }
        }
        float4 zz = {0.f, 0.f, 0.f, 0.f};
        for (int i = (b - 1) * 1024 + t; i < zn4; i += 259 * 1024) zbase[i] = zz;
    }
}

// ---------------------------------------------------------------------------
// mm tile body (r15-verified math; r16-verified aliased reduction buffer:
// tileA doubles as red after the k-loop -> 32 KB LDS for ALL modes, giving
// mm2 (NF=4) 4 blocks/CU instead of 3)
// ---------------------------------------------------------------------------
template <int MODE>
__device__ __forceinline__ void mm_tile_body(
    const float* __restrict__ Km0, const float* __restrict__ Km1,
    const unsigned short* __restrict__ Bhi, const unsigned short* __restrict__ Blo,
    const int* __restrict__ list, int nrows, int tix, int y, int z,
    const float* __restrict__ zpad, float* __restrict__ outf,
    float* tileA, int* rows_s) {
    constexpr int NF = (MODE == 2) ? 4 : 2;
    constexpr int NCTOT = (MODE == 0) ? 32 : ((MODE == 1) ? 64 : 128);
    const int c0 = tix * 16;
    const int tid = threadIdx.x;
    const int lane = tid & 63;
    const int wid = tid >> 6;
    const int row = lane & 15;
    const int kg = lane >> 4;

    __syncthreads();
    if (tid < 16) rows_s[tid] = (c0 + tid < nrows) ? list[c0 + tid] : -1;
    __syncthreads();

    const float* Km = (MODE == 0) ? Km0 : (y ? Km1 : Km0);
    const int zoff = (MODE == 0) ? 0 : y * ((MODE == 1) ? 32 : 64);

    const unsigned short* bph[NF];
    const unsigned short* bpl[NF];
    const int kwb = z * KRANGE + wid * KWAVE;
#pragma unroll
    for (int n = 0; n < NF; ++n) {
        size_t boffs = (size_t)(n * 16 + row) * N_NODES + kwb + kg * 8;
        bph[n] = Bhi + boffs;
        bpl[n] = Blo + boffs;
    }

    f32x4 acc[NF];
#pragma unroll
    for (int n = 0; n < NF; ++n) acc[n] = (f32x4){0.f, 0.f, 0.f, 0.f};

    float* twave = tileA + wid * 2048;    // [2][1024] per wave
    const int srow = lane >> 4;
    const int schk = lane & 15;
#define ISSUE(buf, kofs)                                                       \
    {                                                                          \
        _Pragma("unroll") for (int i = 0; i < 4; ++i) {                        \
            int r = i * 4 + srow;                                              \
            int crw = rows_s[r];                                               \
            int sc = schk ^ (r & 15);                                          \
            const float* gp = (crw >= 0)                                       \
                                  ? Km + (size_t)crw * N_NODES + (kofs) + sc * 4 \
                                  : zpad;                                      \
            gload16(gp, twave + (buf) * 1024 + i * 256);                       \
        }                                                                      \
    }

    ISSUE(0, kwb);
    for (int st = 0; st < NSTAGE; ++st) {
        const int buf = st & 1;
        if (st + 1 < NSTAGE) {
            ISSUE(buf ^ 1, kwb + (st + 1) * 64);
            asm volatile("s_waitcnt vmcnt(4)" ::: "memory");
        } else {
            asm volatile("s_waitcnt vmcnt(0)" ::: "memory");
        }
        __builtin_amdgcn_sched_barrier(0);
        const float* tb = twave + buf * 1024;
#pragma unroll
        for (int ks = 0; ks < 64; ks += 32) {
            int c0i = (kg * 8 + ks) >> 2;
            float4 a0 = *(const float4*)&tb[row * 64 + ((c0i ^ (row & 15)) << 2)];
            float4 a1 = *(const float4*)&tb[row * 64 + (((c0i + 1) ^ (row & 15)) << 2)];
            float av[8] = {a0.x, a0.y, a0.z, a0.w, a1.x, a1.y, a1.z, a1.w};
            s16x8 ah, al;
#pragma unroll
            for (int i = 0; i < 8; ++i) {
                short h = f2bf(av[i]);
                ah[i] = h;
                al[i] = f2bf(av[i] - b2f(h));
            }
            const int bo = st * 64 + ks;
#pragma unroll
            for (int n = 0; n < NF; ++n) {
                s16x8 bh = *(const s16x8*)(bph[n] + bo);
                s16x8 bl = *(const s16x8*)(bpl[n] + bo);
                acc[n] = __builtin_amdgcn_mfma_f32_16x16x32_bf16(al, bh, acc[n], 0, 0, 0);
                acc[n] = __builtin_amdgcn_mfma_f32_16x16x32_bf16(ah, bl, acc[n], 0, 0, 0);
                acc[n] = __builtin_amdgcn_mfma_f32_16x16x32_bf16(ah, bh, acc[n], 0, 0, 0);
            }
        }
        __builtin_amdgcn_sched_barrier(0);
    }
#undef ISSUE

    // reduction buffer aliases tileA (dead for all waves after vmcnt(0)+sync)
    __syncthreads();
    float* redb = tileA;
#pragma unroll
    for (int n = 0; n < NF; ++n)
#pragma unroll
        for (int r = 0; r < 4; ++r)
            redb[wid * (256 * NF) + (kg * 4 + r) * (16 * NF) + (n * 16 + row)] =
                acc[n][r];
    __syncthreads();

    for (int e = tid; e < 256 * NF; e += 256) {
        float s = redb[e] + redb[256 * NF + e] + redb[2 * 256 * NF + e] +
                  redb[3 * 256 * NF + e];
        int orow = e / (16 * NF);
        int ocol = e % (16 * NF);
        int cc = rows_s[orow];
        if (cc >= 0) atomicAdd(&outf[(size_t)cc * NCTOT + zoff + ocol], s);
    }
}

// epilogue element ops (r15-verified math)
__device__ __forceinline__ void ep0_elem(int idx, const float* x, const float* pA,
                                         const float* tau_p, const int* cntA,
                                         unsigned short* uAh, unsigned short* uAl) {
    int d = idx >> 13, c = idx & (N_NODES - 1);
    float u = (float)cntA[c] * (x[(size_t)c * D_IN + d] - tau_p[0] * pA[(size_t)c * 32 + d]);
    short h = f2bf(u);
    uAh[idx] = (unsigned short)h;
    uAl[idx] = (unsigned short)f2bf(u - b2f(h));
}
__device__ __forceinline__ void ep1_elem(int idx, const float* g1, const int* cntB,
                                         unsigned short* uBh, unsigned short* uBl) {
    int d = idx >> 13, c = idx & (N_NODES - 1);
    float u = (float)cntB[c] * g1[(size_t)c * 64 + d];
    short h = f2bf(u);
    uBh[idx] = (unsigned short)h;
    uBl[idx] = (unsigned short)f2bf(u - b2f(h));
}

// ---------------------------------------------------------------------------
// standalone kernels (r15-verified launch structure)
// ---------------------------------------------------------------------------
template <int MODE>
__global__ __launch_bounds__(256) void rows_mmg(
    const float* __restrict__ Km0, const float* __restrict__ Km1,
    const unsigned short* __restrict__ Bhi, const unsigned short* __restrict__ Blo,
    const int* __restrict__ list, const int* __restrict__ nptr, int nidx,
    const float* __restrict__ zpad, float* __restrict__ outf) {
    __shared__ float tileA[4 * 2 * 1024];   // 32 KB (k-loop A dbuf, then red)
    __shared__ int rows_s[16];
    int nrows = nptr[nidx];
    if ((int)blockIdx.x * 16 >= nrows) return;
    mm_tile_body<MODE>(Km0, Km1, Bhi, Blo, list, nrows, blockIdx.x, blockIdx.y,
                       blockIdx.z, zpad, outf, tileA, rows_s);
}

__global__ void ep0_kernel(const float* __restrict__ x, const float* __restrict__ pA,
                           const float* __restrict__ tau_p, const int* __restrict__ cntA,
                           unsigned short* __restrict__ uAh, unsigned short* __restrict__ uAl) {
    int idx = blockIdx.x * 256 + threadIdx.x;
    if (idx < N_NODES * 32) ep0_elem(idx, x, pA, tau_p, cntA, uAh, uAl);
}
__global__ void ep1_kernel(const float* __restrict__ g1, const int* __restrict__ cntB,
                           unsigned short* __restrict__ uBh, unsigned short* __restrict__ uBl) {
    int idx = blockIdx.x * 256 + threadIdx.x;
    if (idx < N_NODES * 64) ep1_elem(idx, g1, cntB, uBh, uBl);
}

// head (r15-verified): z-gather inlined + SAGE conv + MLP + canary
__global__ void head_kernel(const float* __restrict__ g1, const float* __restrict__ g2,
                            const int* __restrict__ n32, const void* __restrict__ eraw,
                            const float* __restrict__ Wself, const float* __restrict__ Wneigh,
                            const float* __restrict__ bconv, const float* __restrict__ W1,
                            const float* __restrict__ b1, const float* __restrict__ W2,
                            const float* __restrict__ b2, const int* __restrict__ flags,
                            float* __restrict__ out) {
    __shared__ float zs[192], za[192], hc[128], hm[64];
    __shared__ int csrc[16];
    int t = threadIdx.x, b = blockIdx.x;
    const int* ei = (const int*)eraw;
    const long long* el = (const long long*)eraw;
    if (t < 16) {
        bool e64 = true;
#pragma unroll
        for (int j = 0; j < 8; ++j) {
            long long a = el[j];
            if (a < 0 || a >= N1) e64 = false;
        }
        long long sv = e64 ? el[b * 16 + t] : (long long)ei[b * 16 + t];
        int si = (sv < 0 || sv >= N1) ? 0 : (int)sv;
        csrc[t] = n32[si];
    }
    __syncthreads();
    if (t < 192) {
        int cb = n32[b];
        zs[t] = (t < 64) ? g1[(size_t)cb * 64 + t] : g2[(size_t)cb * 128 + (t - 64)];
        float s = 0.f;
#pragma unroll
        for (int e = 0; e < 16; ++e) {
            int c = csrc[e];
            s += (t < 64) ? g1[(size_t)c * 64 + t] : g2[(size_t)c * 128 + (t - 64)];
        }
        za[t] = s * (1.0f / 16.0f);
    }
    __syncthreads();
    if (t < 128) {
        float s = bconv[t];
        for (int d = 0; d < 192; ++d)
            s += zs[d] * Wself[d * 128 + t] + za[d] * Wneigh[d * 128 + t];
        hc[t] = s;
    }
    __syncthreads();
    if (t < 64) {
        float s = b1[t];
        for (int h = 0; h < 128; ++h) s += hc[h] * W1[h * 64 + t];
        hm[t] = fmaxf(s, 0.0f);
    }
    __syncthreads();
    if (t < 32) {
        float s = b2[t];
        for (int j = 0; j < 64; ++j) s += hm[j] * W2[j * 32 + t];
        out[(size_t)b * 32 + t] = s;
    }
    __syncthreads();
    if (b == 0 && t == 0) {
        int f = flags[0];
        if (f) out[0] = 100000.0f * (float)f;
    }
}

__global__ void ws_fail_kernel(float* out) {
    if (threadIdx.x == 0 && blockIdx.x == 0) out[0] = 100000.0f;
}

// ---------------------------------------------------------------------------
extern "C" void kernel_launch(void* const* d_in, const int* in_sizes, int n_in,
                              void* d_out, int out_size, void* d_ws, size_t ws_size,
                              hipStream_t stream) {
    const float* x      = (const float*)d_in[0];
    const float* tau    = (const float*)d_in[1];
    const float* L      = (const float*)d_in[2];
    const float* K0     = (const float*)d_in[3];
    const float* K1     = (const float*)d_in[4];
    const float* Wself  = (const float*)d_in[5];
    const float* Wneigh = (const float*)d_in[6];
    const float* bconv  = (const float*)d_in[7];
    const float* W1     = (const float*)d_in[8];
    const float* b1     = (const float*)d_in[9];
    const float* W2     = (const float*)d_in[10];
    const float* b2     = (const float*)d_in[11];
    float* out = (float*)d_out;

    char* ws = (char*)d_ws;
    size_t off = 0;
    int* flags = (int*)(ws + off); off += 256;
    int* cntA  = (int*)(ws + off); off += 32768;
    int* cntB  = (int*)(ws + off); off += 32768;
    int* n32   = (int*)(ws + off); off += 8192;
    int* listA = (int*)(ws + off); off += 32768;
    int* listB = (int*)(ws + off); off += 32768;
    int* listC = (int*)(ws + off); off += 32768;
    float* zpad = (float*)(ws + off); off += 1024;
    float* pA = (float*)(ws + off); off += (size_t)N_NODES * 32 * 4;
    float* g1 = (float*)(ws + off); off += (size_t)N_NODES * 64 * 4;
    float* g2 = (float*)(ws + off); off += (size_t)N_NODES * 128 * 4;
    unsigned short* xh  = (unsigned short*)(ws + off); off += (size_t)32 * N_NODES * 2;
    unsigned short* xl  = (unsigned short*)(ws + off); off += (size_t)32 * N_NODES * 2;
    unsigned short* uAh = (unsigned short*)(ws + off); off += (size_t)32 * N_NODES * 2;
    unsigned short* uAl = (unsigned short*)(ws + off); off += (size_t)32 * N_NODES * 2;
    unsigned short* uBh = (unsigned short*)(ws + off); off += (size_t)64 * N_NODES * 2;
    unsigned short* uBl = (unsigned short*)(ws + off); off += (size_t)64 * N_NODES * 2;
    const size_t needed = off;

    if (ws_size < needed || n_in != 14 || out_size != N0 * 32) {
        ws_fail_kernel<<<1, 64, 0, stream>>>(out);
        return;
    }

    const int zn4 = (int)((1024 + (size_t)(32 + 64 + 128) * N_NODES * 4) / 16);

    // 1) prep: counts/lists/flags + n32 + xt + zero [zpad|pA|g1|g2]
    prep_kernel<<<260, 1024, 0, stream>>>(d_in[12], x, tau, n32, cntA, cntB, listA,
                                          listB, listC, flags, xh, xl, (float4*)zpad,
                                          zn4);
    // 2) diffusion partials: pA += L[rows, kslice] @ x
    rows_mmg<0><<<dim3(384, 1, KZ), 256, 0, stream>>>(L, L, xh, xl, listA, flags + 2,
                                                      0, zpad, pA);
    // 3) uA = cntA*(x - tau*pA)
    ep0_kernel<<<1024, 256, 0, stream>>>(x, pA, tau, cntA, uAh, uAl);
    // 4) hop1 partials: g1 += [K0|K1][rows, kslice] @ uA
    rows_mmg<1><<<dim3(256, 2, KZ), 256, 0, stream>>>(K0, K1, uAh, uAl, listB,
                                                      flags + 2, 1, zpad, g1);
    // 5) uB = cntB * g1
    ep1_kernel<<<2048, 256, 0, stream>>>(g1, cntB, uBh, uBl);
    // 6) hop2 partials: g2 += [K0|K1][rows, kslice] @ uB (col-halves fused, NF=4)
    rows_mmg<2><<<dim3(128, 2, KZ), 256, 0, stream>>>(K0, K1, uBh, uBl, listC,
                                                      flags + 2, 2, zpad, g2);
    // 7) head: z-gather + conv + MLP + canary
    head_kernel<<<1024, 256, 0, stream>>>(g1, g2, n32, d_in[13], Wself, Wneigh, bconv,
                                          W1, b1, W2, b2, flags, out);
}

// Round 18
// 230.420 us; speedup vs baseline: 3.1977x; 1.0463x over previous
//
#include <hip/hip_runtime.h>
#include <hip/hip_bf16.h>

#define N_NODES 8192
#define D_IN 32
#define N3 6144
#define N2 4096
#define N1 2048
#define N0 1024
#define NE 16384
#define KZ 4                     // grid-level k-slices
#define KRANGE (N_NODES / KZ)    // 2048 k per block
#define KWAVE (KRANGE / 4)       // 512 k per wave (4 waves)
#define NSTAGE (KWAVE / 64)      // 8 stages of 64 k

using f32x4 = __attribute__((ext_vector_type(4))) float;
using s16x8 = __attribute__((ext_vector_type(8))) short;

__device__ __forceinline__ short f2bf(float f) {
    union { __hip_bfloat16 b; short s; } u;
    u.b = __float2bfloat16(f);
    return u.s;
}
__device__ __forceinline__ float b2f(short s) {
    unsigned int u = ((unsigned int)(unsigned short)s) << 16;
    float f;
    __builtin_memcpy(&f, &u, 4);
    return f;
}
__device__ __forceinline__ void gload16(const float* g, float* l) {
    __builtin_amdgcn_global_load_lds(
        (const __attribute__((address_space(1))) void*)g,
        (__attribute__((address_space(3))) void*)l, 16, 0, 0);
}

// ---------------------------------------------------------------------------
// prep (r13/r15/r17-verified, verbatim)
// ---------------------------------------------------------------------------
__global__ __launch_bounds__(1024) void prep_kernel(
    const void* __restrict__ nraw, const float* __restrict__ x,
    const float* __restrict__ tau_p, int* __restrict__ n32,
    int* __restrict__ cntA, int* __restrict__ cntB,
    int* __restrict__ listA, int* __restrict__ listB, int* __restrict__ listC,
    int* __restrict__ flags,
    unsigned short* __restrict__ xh, unsigned short* __restrict__ xl,
    float4* __restrict__ zbase, int zn4) {
    __shared__ int lcnt[N_NODES];
    __shared__ float tile[128][33];
    __shared__ int lnum, lfl;
    const int b = blockIdx.x, t = threadIdx.x;
    const int* ni = (const int*)nraw;
    const long long* nl = (const long long*)nraw;

    if (b == 0) {
        bool n64 = true;
#pragma unroll
        for (int j = 0; j < 8; ++j) {
            long long a = nl[j];
            if (a < 0 || a >= N_NODES) n64 = false;
        }
        if (t == 0) { lnum = 0; lfl = 0; }
        for (int i = t; i < N_NODES; i += 1024) lcnt[i] = 0;
        __syncthreads();
        for (int j = t; j < N3; j += 1024) {
            long long v = n64 ? nl[j] : (long long)ni[j];
            if (v < 0 || v >= N_NODES) { atomicOr(&lfl, 2); v = 0; }
            if (j < N1) n32[j] = (int)v;
            atomicAdd(&lcnt[(int)v], 1);
        }
        __syncthreads();
        for (int c = t; c < N_NODES; c += 1024) {
            int cv = lcnt[c];
            cntA[c] = cv;
            if (cv) listA[atomicAdd(&lnum, 1)] = c;
        }
        __syncthreads();
        if (t == 0) { flags[2] = lnum; lnum = 0; }
        __syncthreads();
        for (int i = t; i < N_NODES; i += 1024) lcnt[i] = 0;
        __syncthreads();
        for (int j = t; j < N2; j += 1024) {
            long long v = n64 ? nl[j] : (long long)ni[j];
            v = (v < 0 || v >= N_NODES) ? 0 : v;
            atomicAdd(&lcnt[(int)v], 1);
        }
        __syncthreads();
        for (int c = t; c < N_NODES; c += 1024) {
            int cv = lcnt[c];
            cntB[c] = cv;
            if (cv) listB[atomicAdd(&lnum, 1)] = c;
        }
        __syncthreads();
        if (t == 0) { flags[3] = lnum; lnum = 0; }
        __syncthreads();
        for (int i = t; i < N_NODES; i += 1024) lcnt[i] = 0;
        __syncthreads();
        for (int j = t; j < N1; j += 1024) {
            long long v = n64 ? nl[j] : (long long)ni[j];
            v = (v < 0 || v >= N_NODES) ? 0 : v;
            atomicAdd(&lcnt[(int)v], 1);
        }
        __syncthreads();
        for (int c = t; c < N_NODES; c += 1024) {
            if (lcnt[c]) listC[atomicAdd(&lnum, 1)] = c;
        }
        __syncthreads();
        if (t == 0) {
            flags[4] = lnum;
            int f = lfl;
            if (fabsf(tau_p[0] - 0.1f) > 1e-6f) f |= 32;
            flags[0] = f;
        }
    } else {
        if (b <= 64) {
            const int c0 = (b - 1) * 128;
            const int d = t & 31, cc = t >> 5;
#pragma unroll
            for (int i = 0; i < 4; ++i)
                tile[cc + 32 * i][d] = x[(size_t)(c0 + cc + 32 * i) * D_IN + d];
            __syncthreads();
#pragma unroll
            for (int i = 0; i < 4; ++i) {
                int idx = t + 1024 * i;
                int dd = idx >> 7;
                int jj = idx & 127;
                float v = tile[jj][dd];
                short h = f2bf(v);
                xh[(size_t)dd * N_NODES + c0 + jj] = (unsigned short)h;
                xl[(size_t)dd * N_NODES + c0 + jj] = (unsigned short)f2bf(v - b2f(h));
            }
        }
        float4 zz = {0.f, 0.f, 0.f, 0.f};
        for (int i = (b - 1) * 1024 + t; i < zn4; i += 259 * 1024) zbase[i] = zz;
    }
}

// ---------------------------------------------------------------------------
// mm tile body. r17 base + COUNTED-VMCNT FIX: all current-stage B fragments
// are register-loaded BEFORE the next-stage A prefetch is issued, so the
// compiler's B-use waits complete without draining the A pipeline. Per-lane
// queue at the wait: A[st](4,old) + B[st](8) + A[st+1](4,young) -> vmcnt(4)
// leaves exactly the next A-prefetch in flight across the MFMA stage.
// NF=2 everywhere (mm2 uses the r12-verified y=0..3 col-slice mapping).
// ---------------------------------------------------------------------------
template <int MODE>
__device__ __forceinline__ void mm_tile_body(
    const float* __restrict__ Km0, const float* __restrict__ Km1,
    const unsigned short* __restrict__ Bhi, const unsigned short* __restrict__ Blo,
    const int* __restrict__ list, int nrows, int tix, int y, int z,
    const float* __restrict__ zpad, float* __restrict__ outf,
    float* tileA, int* rows_s) {
    constexpr int NF = 2;
    constexpr int NCTOT = (MODE == 0) ? 32 : ((MODE == 1) ? 64 : 128);
    const int c0 = tix * 16;
    const int tid = threadIdx.x;
    const int lane = tid & 63;
    const int wid = tid >> 6;
    const int row = lane & 15;
    const int kg = lane >> 4;

    __syncthreads();
    if (tid < 16) rows_s[tid] = (c0 + tid < nrows) ? list[c0 + tid] : -1;
    __syncthreads();

    const float* Km;
    int boff, zoff;
    if constexpr (MODE == 2) {
        Km = (y >> 1) ? Km1 : Km0;
        boff = (y & 1) * 32;
        zoff = y * 32;
    } else if constexpr (MODE == 1) {
        Km = y ? Km1 : Km0;
        boff = 0;
        zoff = y * 32;
    } else {
        Km = Km0;
        boff = 0;
        zoff = 0;
    }

    const unsigned short* bph[NF];
    const unsigned short* bpl[NF];
    const int kwb = z * KRANGE + wid * KWAVE;
#pragma unroll
    for (int n = 0; n < NF; ++n) {
        size_t boffs = (size_t)(boff + n * 16 + row) * N_NODES + kwb + kg * 8;
        bph[n] = Bhi + boffs;
        bpl[n] = Blo + boffs;
    }

    f32x4 acc[NF];
#pragma unroll
    for (int n = 0; n < NF; ++n) acc[n] = (f32x4){0.f, 0.f, 0.f, 0.f};

    float* twave = tileA + wid * 2048;    // [2][1024] per wave
    const int srow = lane >> 4;
    const int schk = lane & 15;
#define ISSUE(buf, kofs)                                                       \
    {                                                                          \
        _Pragma("unroll") for (int i = 0; i < 4; ++i) {                        \
            int r = i * 4 + srow;                                              \
            int crw = rows_s[r];                                               \
            int sc = schk ^ (r & 15);                                          \
            const float* gp = (crw >= 0)                                       \
                                  ? Km + (size_t)crw * N_NODES + (kofs) + sc * 4 \
                                  : zpad;                                      \
            gload16(gp, twave + (buf) * 1024 + i * 256);                       \
        }                                                                      \
    }

    ISSUE(0, kwb);
    for (int st = 0; st < NSTAGE; ++st) {
        const int buf = st & 1;
        const int bo = st * 64;
        // 1) current-stage B fragments -> registers (8 loads, before A issue)
        s16x8 bhr[2][NF], blr[2][NF];
#pragma unroll
        for (int h = 0; h < 2; ++h)
#pragma unroll
            for (int n = 0; n < NF; ++n) {
                bhr[h][n] = *(const s16x8*)(bph[n] + bo + h * 32);
                blr[h][n] = *(const s16x8*)(bpl[n] + bo + h * 32);
            }
        // 2) next-stage A prefetch, then counted wait
        if (st + 1 < NSTAGE) {
            ISSUE(buf ^ 1, kwb + (st + 1) * 64);
            asm volatile("s_waitcnt vmcnt(4)" ::: "memory");
        } else {
            asm volatile("s_waitcnt vmcnt(0)" ::: "memory");
        }
        __builtin_amdgcn_sched_barrier(0);
        // 3) MFMA on LDS A[st] + registered B[st] (no VMEM waits inside)
        const float* tb = twave + buf * 1024;
#pragma unroll
        for (int h = 0; h < 2; ++h) {
            const int ks = h * 32;
            int c0i = (kg * 8 + ks) >> 2;
            float4 a0 = *(const float4*)&tb[row * 64 + ((c0i ^ (row & 15)) << 2)];
            float4 a1 = *(const float4*)&tb[row * 64 + (((c0i + 1) ^ (row & 15)) << 2)];
            float av[8] = {a0.x, a0.y, a0.z, a0.w, a1.x, a1.y, a1.z, a1.w};
            s16x8 ah, al;
#pragma unroll
            for (int i = 0; i < 8; ++i) {
                short hh = f2bf(av[i]);
                ah[i] = hh;
                al[i] = f2bf(av[i] - b2f(hh));
            }
#pragma unroll
            for (int n = 0; n < NF; ++n) {
                acc[n] = __builtin_amdgcn_mfma_f32_16x16x32_bf16(al, bhr[h][n], acc[n], 0, 0, 0);
                acc[n] = __builtin_amdgcn_mfma_f32_16x16x32_bf16(ah, blr[h][n], acc[n], 0, 0, 0);
                acc[n] = __builtin_amdgcn_mfma_f32_16x16x32_bf16(ah, bhr[h][n], acc[n], 0, 0, 0);
            }
        }
        __builtin_amdgcn_sched_barrier(0);
    }
#undef ISSUE

    // reduction buffer aliases tileA (dead for all waves after vmcnt(0)+sync)
    __syncthreads();
    float* redb = tileA;
#pragma unroll
    for (int n = 0; n < NF; ++n)
#pragma unroll
        for (int r = 0; r < 4; ++r)
            redb[wid * (256 * NF) + (kg * 4 + r) * (16 * NF) + (n * 16 + row)] =
                acc[n][r];
    __syncthreads();

    for (int e = tid; e < 256 * NF; e += 256) {
        float s = redb[e] + redb[256 * NF + e] + redb[2 * 256 * NF + e] +
                  redb[3 * 256 * NF + e];
        int orow = e / (16 * NF);
        int ocol = e % (16 * NF);
        int cc = rows_s[orow];
        if (cc >= 0) atomicAdd(&outf[(size_t)cc * NCTOT + zoff + ocol], s);
    }
}

// epilogue element ops (r15-verified math)
__device__ __forceinline__ void ep0_elem(int idx, const float* x, const float* pA,
                                         const float* tau_p, const int* cntA,
                                         unsigned short* uAh, unsigned short* uAl) {
    int d = idx >> 13, c = idx & (N_NODES - 1);
    float u = (float)cntA[c] * (x[(size_t)c * D_IN + d] - tau_p[0] * pA[(size_t)c * 32 + d]);
    short h = f2bf(u);
    uAh[idx] = (unsigned short)h;
    uAl[idx] = (unsigned short)f2bf(u - b2f(h));
}
__device__ __forceinline__ void ep1_elem(int idx, const float* g1, const int* cntB,
                                         unsigned short* uBh, unsigned short* uBl) {
    int d = idx >> 13, c = idx & (N_NODES - 1);
    float u = (float)cntB[c] * g1[(size_t)c * 64 + d];
    short h = f2bf(u);
    uBh[idx] = (unsigned short)h;
    uBl[idx] = (unsigned short)f2bf(u - b2f(h));
}

// ---------------------------------------------------------------------------
// standalone kernels
// ---------------------------------------------------------------------------
template <int MODE>
__global__ __launch_bounds__(256, 4) void rows_mmg(
    const float* __restrict__ Km0, const float* __restrict__ Km1,
    const unsigned short* __restrict__ Bhi, const unsigned short* __restrict__ Blo,
    const int* __restrict__ list, const int* __restrict__ nptr, int nidx,
    const float* __restrict__ zpad, float* __restrict__ outf) {
    __shared__ float tileA[4 * 2 * 1024];   // 32 KB (k-loop A dbuf, then red)
    __shared__ int rows_s[16];
    int nrows = nptr[nidx];
    if ((int)blockIdx.x * 16 >= nrows) return;
    mm_tile_body<MODE>(Km0, Km1, Bhi, Blo, list, nrows, blockIdx.x, blockIdx.y,
                       blockIdx.z, zpad, outf, tileA, rows_s);
}

__global__ void ep0_kernel(const float* __restrict__ x, const float* __restrict__ pA,
                           const float* __restrict__ tau_p, const int* __restrict__ cntA,
                           unsigned short* __restrict__ uAh, unsigned short* __restrict__ uAl) {
    int idx = blockIdx.x * 256 + threadIdx.x;
    if (idx < N_NODES * 32) ep0_elem(idx, x, pA, tau_p, cntA, uAh, uAl);
}
__global__ void ep1_kernel(const float* __restrict__ g1, const int* __restrict__ cntB,
                           unsigned short* __restrict__ uBh, unsigned short* __restrict__ uBl) {
    int idx = blockIdx.x * 256 + threadIdx.x;
    if (idx < N_NODES * 64) ep1_elem(idx, g1, cntB, uBh, uBl);
}

// head (r15/r17-verified): z-gather inlined + SAGE conv + MLP + canary
__global__ void head_kernel(const float* __restrict__ g1, const float* __restrict__ g2,
                            const int* __restrict__ n32, const void* __restrict__ eraw,
                            const float* __restrict__ Wself, const float* __restrict__ Wneigh,
                            const float* __restrict__ bconv, const float* __restrict__ W1,
                            const float* __restrict__ b1, const float* __restrict__ W2,
                            const float* __restrict__ b2, const int* __restrict__ flags,
                            float* __restrict__ out) {
    __shared__ float zs[192], za[192], hc[128], hm[64];
    __shared__ int csrc[16];
    int t = threadIdx.x, b = blockIdx.x;
    const int* ei = (const int*)eraw;
    const long long* el = (const long long*)eraw;
    if (t < 16) {
        bool e64 = true;
#pragma unroll
        for (int j = 0; j < 8; ++j) {
            long long a = el[j];
            if (a < 0 || a >= N1) e64 = false;
        }
        long long sv = e64 ? el[b * 16 + t] : (long long)ei[b * 16 + t];
        int si = (sv < 0 || sv >= N1) ? 0 : (int)sv;
        csrc[t] = n32[si];
    }
    __syncthreads();
    if (t < 192) {
        int cb = n32[b];
        zs[t] = (t < 64) ? g1[(size_t)cb * 64 + t] : g2[(size_t)cb * 128 + (t - 64)];
        float s = 0.f;
#pragma unroll
        for (int e = 0; e < 16; ++e) {
            int c = csrc[e];
            s += (t < 64) ? g1[(size_t)c * 64 + t] : g2[(size_t)c * 128 + (t - 64)];
        }
        za[t] = s * (1.0f / 16.0f);
    }
    __syncthreads();
    if (t < 128) {
        float s = bconv[t];
        for (int d = 0; d < 192; ++d)
            s += zs[d] * Wself[d * 128 + t] + za[d] * Wneigh[d * 128 + t];
        hc[t] = s;
    }
    __syncthreads();
    if (t < 64) {
        float s = b1[t];
        for (int h = 0; h < 128; ++h) s += hc[h] * W1[h * 64 + t];
        hm[t] = fmaxf(s, 0.0f);
    }
    __syncthreads();
    if (t < 32) {
        float s = b2[t];
        for (int j = 0; j < 64; ++j) s += hm[j] * W2[j * 32 + t];
        out[(size_t)b * 32 + t] = s;
    }
    __syncthreads();
    if (b == 0 && t == 0) {
        int f = flags[0];
        if (f) out[0] = 100000.0f * (float)f;
    }
}

__global__ void ws_fail_kernel(float* out) {
    if (threadIdx.x == 0 && blockIdx.x == 0) out[0] = 100000.0f;
}

// ---------------------------------------------------------------------------
extern "C" void kernel_launch(void* const* d_in, const int* in_sizes, int n_in,
                              void* d_out, int out_size, void* d_ws, size_t ws_size,
                              hipStream_t stream) {
    const float* x      = (const float*)d_in[0];
    const float* tau    = (const float*)d_in[1];
    const float* L      = (const float*)d_in[2];
    const float* K0     = (const float*)d_in[3];
    const float* K1     = (const float*)d_in[4];
    const float* Wself  = (const float*)d_in[5];
    const float* Wneigh = (const float*)d_in[6];
    const float* bconv  = (const float*)d_in[7];
    const float* W1     = (const float*)d_in[8];
    const float* b1     = (const float*)d_in[9];
    const float* W2     = (const float*)d_in[10];
    const float* b2     = (const float*)d_in[11];
    float* out = (float*)d_out;

    char* ws = (char*)d_ws;
    size_t off = 0;
    int* flags = (int*)(ws + off); off += 256;
    int* cntA  = (int*)(ws + off); off += 32768;
    int* cntB  = (int*)(ws + off); off += 32768;
    int* n32   = (int*)(ws + off); off += 8192;
    int* listA = (int*)(ws + off); off += 32768;
    int* listB = (int*)(ws + off); off += 32768;
    int* listC = (int*)(ws + off); off += 32768;
    float* zpad = (float*)(ws + off); off += 1024;
    float* pA = (float*)(ws + off); off += (size_t)N_NODES * 32 * 4;
    float* g1 = (float*)(ws + off); off += (size_t)N_NODES * 64 * 4;
    float* g2 = (float*)(ws + off); off += (size_t)N_NODES * 128 * 4;
    unsigned short* xh  = (unsigned short*)(ws + off); off += (size_t)32 * N_NODES * 2;
    unsigned short* xl  = (unsigned short*)(ws + off); off += (size_t)32 * N_NODES * 2;
    unsigned short* uAh = (unsigned short*)(ws + off); off += (size_t)32 * N_NODES * 2;
    unsigned short* uAl = (unsigned short*)(ws + off); off += (size_t)32 * N_NODES * 2;
    unsigned short* uBh = (unsigned short*)(ws + off); off += (size_t)64 * N_NODES * 2;
    unsigned short* uBl = (unsigned short*)(ws + off); off += (size_t)64 * N_NODES * 2;
    const size_t needed = off;

    if (ws_size < needed || n_in != 14 || out_size != N0 * 32) {
        ws_fail_kernel<<<1, 64, 0, stream>>>(out);
        return;
    }

    const int zn4 = (int)((1024 + (size_t)(32 + 64 + 128) * N_NODES * 4) / 16);

    // 1) prep: counts/lists/flags + n32 + xt + zero [zpad|pA|g1|g2]
    prep_kernel<<<260, 1024, 0, stream>>>(d_in[12], x, tau, n32, cntA, cntB, listA,
                                          listB, listC, flags, xh, xl, (float4*)zpad,
                                          zn4);
    // 2) diffusion partials: pA += L[rows, kslice] @ x
    rows_mmg<0><<<dim3(384, 1, KZ), 256, 0, stream>>>(L, L, xh, xl, listA, flags + 2,
                                                      0, zpad, pA);
    // 3) uA = cntA*(x - tau*pA)
    ep0_kernel<<<1024, 256, 0, stream>>>(x, pA, tau, cntA, uAh, uAl);
    // 4) hop1 partials: g1 += [K0|K1][rows, kslice] @ uA
    rows_mmg<1><<<dim3(256, 2, KZ), 256, 0, stream>>>(K0, K1, uAh, uAl, listB,
                                                      flags + 2, 1, zpad, g1);
    // 5) uB = cntB * g1
    ep1_kernel<<<2048, 256, 0, stream>>>(g1, cntB, uBh, uBl);
    // 6) hop2 partials: g2 += [K0|K1][rows, kslice] @ uB (r12-verified y=0..3 map)
    rows_mmg<2><<<dim3(128, 4, KZ), 256, 0, stream>>>(K0, K1, uBh, uBl, listC,
                                                      flags + 2, 2, zpad, g2);
    // 7) head: z-gather + conv + MLP + canary
    head_kernel<<<1024, 256, 0, stream>>>(g1, g2, n32, d_in[13], Wself, Wneigh, bconv,
                                          W1, b1, W2, b2, flags, out);
}

// Round 19
// 227.469 us; speedup vs baseline: 3.2392x; 1.0130x over previous
//
#include <hip/hip_runtime.h>
#include <hip/hip_bf16.h>

#define N_NODES 8192
#define D_IN 32
#define N3 6144
#define N2 4096
#define N1 2048
#define N0 1024
#define NE 16384
#define KZ 4                     // grid-level k-slices
#define KRANGE (N_NODES / KZ)    // 2048 k per block
#define KWAVE (KRANGE / 4)       // 512 k per wave (4 waves)
#define NSTAGE (KWAVE / 64)      // 8 stages of 64 k

using f32x4 = __attribute__((ext_vector_type(4))) float;
using s16x8 = __attribute__((ext_vector_type(8))) short;

__device__ __forceinline__ short f2bf(float f) {
    union { __hip_bfloat16 b; short s; } u;
    u.b = __float2bfloat16(f);
    return u.s;
}
__device__ __forceinline__ float b2f(short s) {
    unsigned int u = ((unsigned int)(unsigned short)s) << 16;
    float f;
    __builtin_memcpy(&f, &u, 4);
    return f;
}
__device__ __forceinline__ void gload16(const float* g, float* l) {
    __builtin_amdgcn_global_load_lds(
        (const __attribute__((address_space(1))) void*)g,
        (__attribute__((address_space(3))) void*)l, 16, 0, 0);
}

// ---------------------------------------------------------------------------
// prep (r13/r15/r17-verified, verbatim)
// ---------------------------------------------------------------------------
__global__ __launch_bounds__(1024) void prep_kernel(
    const void* __restrict__ nraw, const float* __restrict__ x,
    const float* __restrict__ tau_p, int* __restrict__ n32,
    int* __restrict__ cntA, int* __restrict__ cntB,
    int* __restrict__ listA, int* __restrict__ listB, int* __restrict__ listC,
    int* __restrict__ flags,
    unsigned short* __restrict__ xh, unsigned short* __restrict__ xl,
    float4* __restrict__ zbase, int zn4) {
    __shared__ int lcnt[N_NODES];
    __shared__ float tile[128][33];
    __shared__ int lnum, lfl;
    const int b = blockIdx.x, t = threadIdx.x;
    const int* ni = (const int*)nraw;
    const long long* nl = (const long long*)nraw;

    if (b == 0) {
        bool n64 = true;
#pragma unroll
        for (int j = 0; j < 8; ++j) {
            long long a = nl[j];
            if (a < 0 || a >= N_NODES) n64 = false;
        }
        if (t == 0) { lnum = 0; lfl = 0; }
        for (int i = t; i < N_NODES; i += 1024) lcnt[i] = 0;
        __syncthreads();
        for (int j = t; j < N3; j += 1024) {
            long long v = n64 ? nl[j] : (long long)ni[j];
            if (v < 0 || v >= N_NODES) { atomicOr(&lfl, 2); v = 0; }
            if (j < N1) n32[j] = (int)v;
            atomicAdd(&lcnt[(int)v], 1);
        }
        __syncthreads();
        for (int c = t; c < N_NODES; c += 1024) {
            int cv = lcnt[c];
            cntA[c] = cv;
            if (cv) listA[atomicAdd(&lnum, 1)] = c;
        }
        __syncthreads();
        if (t == 0) { flags[2] = lnum; lnum = 0; }
        __syncthreads();
        for (int i = t; i < N_NODES; i += 1024) lcnt[i] = 0;
        __syncthreads();
        for (int j = t; j < N2; j += 1024) {
            long long v = n64 ? nl[j] : (long long)ni[j];
            v = (v < 0 || v >= N_NODES) ? 0 : v;
            atomicAdd(&lcnt[(int)v], 1);
        }
        __syncthreads();
        for (int c = t; c < N_NODES; c += 1024) {
            int cv = lcnt[c];
            cntB[c] = cv;
            if (cv) listB[atomicAdd(&lnum, 1)] = c;
        }
        __syncthreads();
        if (t == 0) { flags[3] = lnum; lnum = 0; }
        __syncthreads();
        for (int i = t; i < N_NODES; i += 1024) lcnt[i] = 0;
        __syncthreads();
        for (int j = t; j < N1; j += 1024) {
            long long v = n64 ? nl[j] : (long long)ni[j];
            v = (v < 0 || v >= N_NODES) ? 0 : v;
            atomicAdd(&lcnt[(int)v], 1);
        }
        __syncthreads();
        for (int c = t; c < N_NODES; c += 1024) {
            if (lcnt[c]) listC[atomicAdd(&lnum, 1)] = c;
        }
        __syncthreads();
        if (t == 0) {
            flags[4] = lnum;
            int f = lfl;
            if (fabsf(tau_p[0] - 0.1f) > 1e-6f) f |= 32;
            flags[0] = f;
        }
    } else {
        if (b <= 64) {
            const int c0 = (b - 1) * 128;
            const int d = t & 31, cc = t >> 5;
#pragma unroll
            for (int i = 0; i < 4; ++i)
                tile[cc + 32 * i][d] = x[(size_t)(c0 + cc + 32 * i) * D_IN + d];
            __syncthreads();
#pragma unroll
            for (int i = 0; i < 4; ++i) {
                int idx = t + 1024 * i;
                int dd = idx >> 7;
                int jj = idx & 127;
                float v = tile[jj][dd];
                short h = f2bf(v);
                xh[(size_t)dd * N_NODES + c0 + jj] = (unsigned short)h;
                xl[(size_t)dd * N_NODES + c0 + jj] = (unsigned short)f2bf(v - b2f(h));
            }
        }
        float4 zz = {0.f, 0.f, 0.f, 0.f};
        for (int i = (b - 1) * 1024 + t; i < zn4; i += 259 * 1024) zbase[i] = zz;
    }
}

// ---------------------------------------------------------------------------
// mm tile body. r18 base + B REGISTER DOUBLE-BUFFER: prologue loads B[0];
// each stage issues A[st+1] (async LDS), waits vmcnt(4) (completes A[st] and
// B[st], keeps A[st+1] flying), then issues B[st+1] register loads BEFORE the
// MFMA block so their L2 latency hides under the MFMA+split VALU work.
// #pragma unroll keeps all breg indices compile-time (no scratch, rule 20);
// sched_barrier(0) pins issue order (rule 18).
// ---------------------------------------------------------------------------
template <int MODE>
__device__ __forceinline__ void mm_tile_body(
    const float* __restrict__ Km0, const float* __restrict__ Km1,
    const unsigned short* __restrict__ Bhi, const unsigned short* __restrict__ Blo,
    const int* __restrict__ list, int nrows, int tix, int y, int z,
    const float* __restrict__ zpad, float* __restrict__ outf,
    float* tileA, int* rows_s) {
    constexpr int NF = 2;
    constexpr int NCTOT = (MODE == 0) ? 32 : ((MODE == 1) ? 64 : 128);
    const int c0 = tix * 16;
    const int tid = threadIdx.x;
    const int lane = tid & 63;
    const int wid = tid >> 6;
    const int row = lane & 15;
    const int kg = lane >> 4;

    __syncthreads();
    if (tid < 16) rows_s[tid] = (c0 + tid < nrows) ? list[c0 + tid] : -1;
    __syncthreads();

    const float* Km;
    int boff, zoff;
    if constexpr (MODE == 2) {
        Km = (y >> 1) ? Km1 : Km0;
        boff = (y & 1) * 32;
        zoff = y * 32;
    } else if constexpr (MODE == 1) {
        Km = y ? Km1 : Km0;
        boff = 0;
        zoff = y * 32;
    } else {
        Km = Km0;
        boff = 0;
        zoff = 0;
    }

    const unsigned short* bph[NF];
    const unsigned short* bpl[NF];
    const int kwb = z * KRANGE + wid * KWAVE;
#pragma unroll
    for (int n = 0; n < NF; ++n) {
        size_t boffs = (size_t)(boff + n * 16 + row) * N_NODES + kwb + kg * 8;
        bph[n] = Bhi + boffs;
        bpl[n] = Blo + boffs;
    }

    f32x4 acc[NF];
#pragma unroll
    for (int n = 0; n < NF; ++n) acc[n] = (f32x4){0.f, 0.f, 0.f, 0.f};

    float* twave = tileA + wid * 2048;    // [2][1024] per wave
    const int srow = lane >> 4;
    const int schk = lane & 15;
#define ISSUE(buf, kofs)                                                       \
    {                                                                          \
        _Pragma("unroll") for (int i = 0; i < 4; ++i) {                        \
            int r = i * 4 + srow;                                              \
            int crw = rows_s[r];                                               \
            int sc = schk ^ (r & 15);                                          \
            const float* gp = (crw >= 0)                                       \
                                  ? Km + (size_t)crw * N_NODES + (kofs) + sc * 4 \
                                  : zpad;                                      \
            gload16(gp, twave + (buf) * 1024 + i * 256);                       \
        }                                                                      \
    }
    // B frag loads for stage boundary 'bo' into parity slot 'pb'
    s16x8 bhr[2][2][NF], blr[2][2][NF];   // [parity][h][n]
#define LOADB(pb, bo)                                                          \
    {                                                                          \
        _Pragma("unroll") for (int h = 0; h < 2; ++h)                          \
            _Pragma("unroll") for (int n = 0; n < NF; ++n) {                   \
                bhr[pb][h][n] = *(const s16x8*)(bph[n] + (bo) + h * 32);       \
                blr[pb][h][n] = *(const s16x8*)(bpl[n] + (bo) + h * 32);       \
            }                                                                  \
    }

    ISSUE(0, kwb);
    LOADB(0, 0);
#pragma unroll
    for (int st = 0; st < NSTAGE; ++st) {
        const int buf = st & 1;
        const int pb = st & 1;
        if (st + 1 < NSTAGE) {
            ISSUE(buf ^ 1, kwb + (st + 1) * 64);
            asm volatile("s_waitcnt vmcnt(4)" ::: "memory");
            __builtin_amdgcn_sched_barrier(0);
            LOADB(pb ^ 1, (st + 1) * 64);      // next-stage B, hides under MFMA
            __builtin_amdgcn_sched_barrier(0);
        } else {
            asm volatile("s_waitcnt vmcnt(0)" ::: "memory");
            __builtin_amdgcn_sched_barrier(0);
        }
        // MFMA on LDS A[st] + registered B[st]
        const float* tb = twave + buf * 1024;
#pragma unroll
        for (int h = 0; h < 2; ++h) {
            const int ks = h * 32;
            int c0i = (kg * 8 + ks) >> 2;
            float4 a0 = *(const float4*)&tb[row * 64 + ((c0i ^ (row & 15)) << 2)];
            float4 a1 = *(const float4*)&tb[row * 64 + (((c0i + 1) ^ (row & 15)) << 2)];
            float av[8] = {a0.x, a0.y, a0.z, a0.w, a1.x, a1.y, a1.z, a1.w};
            s16x8 ah, al;
#pragma unroll
            for (int i = 0; i < 8; ++i) {
                short hh = f2bf(av[i]);
                ah[i] = hh;
                al[i] = f2bf(av[i] - b2f(hh));
            }
#pragma unroll
            for (int n = 0; n < NF; ++n) {
                acc[n] = __builtin_amdgcn_mfma_f32_16x16x32_bf16(al, bhr[pb][h][n], acc[n], 0, 0, 0);
                acc[n] = __builtin_amdgcn_mfma_f32_16x16x32_bf16(ah, blr[pb][h][n], acc[n], 0, 0, 0);
                acc[n] = __builtin_amdgcn_mfma_f32_16x16x32_bf16(ah, bhr[pb][h][n], acc[n], 0, 0, 0);
            }
        }
        __builtin_amdgcn_sched_barrier(0);
    }
#undef ISSUE
#undef LOADB

    // reduction buffer aliases tileA (dead for all waves after vmcnt(0)+sync)
    __syncthreads();
    float* redb = tileA;
#pragma unroll
    for (int n = 0; n < NF; ++n)
#pragma unroll
        for (int r = 0; r < 4; ++r)
            redb[wid * (256 * NF) + (kg * 4 + r) * (16 * NF) + (n * 16 + row)] =
                acc[n][r];
    __syncthreads();

    for (int e = tid; e < 256 * NF; e += 256) {
        float s = redb[e] + redb[256 * NF + e] + redb[2 * 256 * NF + e] +
                  redb[3 * 256 * NF + e];
        int orow = e / (16 * NF);
        int ocol = e % (16 * NF);
        int cc = rows_s[orow];
        if (cc >= 0) atomicAdd(&outf[(size_t)cc * NCTOT + zoff + ocol], s);
    }
}

// epilogue element ops (r15-verified math)
__device__ __forceinline__ void ep0_elem(int idx, const float* x, const float* pA,
                                         const float* tau_p, const int* cntA,
                                         unsigned short* uAh, unsigned short* uAl) {
    int d = idx >> 13, c = idx & (N_NODES - 1);
    float u = (float)cntA[c] * (x[(size_t)c * D_IN + d] - tau_p[0] * pA[(size_t)c * 32 + d]);
    short h = f2bf(u);
    uAh[idx] = (unsigned short)h;
    uAl[idx] = (unsigned short)f2bf(u - b2f(h));
}
__device__ __forceinline__ void ep1_elem(int idx, const float* g1, const int* cntB,
                                         unsigned short* uBh, unsigned short* uBl) {
    int d = idx >> 13, c = idx & (N_NODES - 1);
    float u = (float)cntB[c] * g1[(size_t)c * 64 + d];
    short h = f2bf(u);
    uBh[idx] = (unsigned short)h;
    uBl[idx] = (unsigned short)f2bf(u - b2f(h));
}

// ---------------------------------------------------------------------------
// standalone kernels
// ---------------------------------------------------------------------------
template <int MODE>
__global__ __launch_bounds__(256, 4) void rows_mmg(
    const float* __restrict__ Km0, const float* __restrict__ Km1,
    const unsigned short* __restrict__ Bhi, const unsigned short* __restrict__ Blo,
    const int* __restrict__ list, const int* __restrict__ nptr, int nidx,
    const float* __restrict__ zpad, float* __restrict__ outf) {
    __shared__ float tileA[4 * 2 * 1024];   // 32 KB (k-loop A dbuf, then red)
    __shared__ int rows_s[16];
    int nrows = nptr[nidx];
    if ((int)blockIdx.x * 16 >= nrows) return;
    mm_tile_body<MODE>(Km0, Km1, Bhi, Blo, list, nrows, blockIdx.x, blockIdx.y,
                       blockIdx.z, zpad, outf, tileA, rows_s);
}

__global__ void ep0_kernel(const float* __restrict__ x, const float* __restrict__ pA,
                           const float* __restrict__ tau_p, const int* __restrict__ cntA,
                           unsigned short* __restrict__ uAh, unsigned short* __restrict__ uAl) {
    int idx = blockIdx.x * 256 + threadIdx.x;
    if (idx < N_NODES * 32) ep0_elem(idx, x, pA, tau_p, cntA, uAh, uAl);
}
__global__ void ep1_kernel(const float* __restrict__ g1, const int* __restrict__ cntB,
                           unsigned short* __restrict__ uBh, unsigned short* __restrict__ uBl) {
    int idx = blockIdx.x * 256 + threadIdx.x;
    if (idx < N_NODES * 64) ep1_elem(idx, g1, cntB, uBh, uBl);
}

// head (r15/r17-verified): z-gather inlined + SAGE conv + MLP + canary
__global__ void head_kernel(const float* __restrict__ g1, const float* __restrict__ g2,
                            const int* __restrict__ n32, const void* __restrict__ eraw,
                            const float* __restrict__ Wself, const float* __restrict__ Wneigh,
                            const float* __restrict__ bconv, const float* __restrict__ W1,
                            const float* __restrict__ b1, const float* __restrict__ W2,
                            const float* __restrict__ b2, const int* __restrict__ flags,
                            float* __restrict__ out) {
    __shared__ float zs[192], za[192], hc[128], hm[64];
    __shared__ int csrc[16];
    int t = threadIdx.x, b = blockIdx.x;
    const int* ei = (const int*)eraw;
    const long long* el = (const long long*)eraw;
    if (t < 16) {
        bool e64 = true;
#pragma unroll
        for (int j = 0; j < 8; ++j) {
            long long a = el[j];
            if (a < 0 || a >= N1) e64 = false;
        }
        long long sv = e64 ? el[b * 16 + t] : (long long)ei[b * 16 + t];
        int si = (sv < 0 || sv >= N1) ? 0 : (int)sv;
        csrc[t] = n32[si];
    }
    __syncthreads();
    if (t < 192) {
        int cb = n32[b];
        zs[t] = (t < 64) ? g1[(size_t)cb * 64 + t] : g2[(size_t)cb * 128 + (t - 64)];
        float s = 0.f;
#pragma unroll
        for (int e = 0; e < 16; ++e) {
            int c = csrc[e];
            s += (t < 64) ? g1[(size_t)c * 64 + t] : g2[(size_t)c * 128 + (t - 64)];
        }
        za[t] = s * (1.0f / 16.0f);
    }
    __syncthreads();
    if (t < 128) {
        float s = bconv[t];
        for (int d = 0; d < 192; ++d)
            s += zs[d] * Wself[d * 128 + t] + za[d] * Wneigh[d * 128 + t];
        hc[t] = s;
    }
    __syncthreads();
    if (t < 64) {
        float s = b1[t];
        for (int h = 0; h < 128; ++h) s += hc[h] * W1[h * 64 + t];
        hm[t] = fmaxf(s, 0.0f);
    }
    __syncthreads();
    if (t < 32) {
        float s = b2[t];
        for (int j = 0; j < 64; ++j) s += hm[j] * W2[j * 32 + t];
        out[(size_t)b * 32 + t] = s;
    }
    __syncthreads();
    if (b == 0 && t == 0) {
        int f = flags[0];
        if (f) out[0] = 100000.0f * (float)f;
    }
}

__global__ void ws_fail_kernel(float* out) {
    if (threadIdx.x == 0 && blockIdx.x == 0) out[0] = 100000.0f;
}

// ---------------------------------------------------------------------------
extern "C" void kernel_launch(void* const* d_in, const int* in_sizes, int n_in,
                              void* d_out, int out_size, void* d_ws, size_t ws_size,
                              hipStream_t stream) {
    const float* x      = (const float*)d_in[0];
    const float* tau    = (const float*)d_in[1];
    const float* L      = (const float*)d_in[2];
    const float* K0     = (const float*)d_in[3];
    const float* K1     = (const float*)d_in[4];
    const float* Wself  = (const float*)d_in[5];
    const float* Wneigh = (const float*)d_in[6];
    const float* bconv  = (const float*)d_in[7];
    const float* W1     = (const float*)d_in[8];
    const float* b1     = (const float*)d_in[9];
    const float* W2     = (const float*)d_in[10];
    const float* b2     = (const float*)d_in[11];
    float* out = (float*)d_out;

    char* ws = (char*)d_ws;
    size_t off = 0;
    int* flags = (int*)(ws + off); off += 256;
    int* cntA  = (int*)(ws + off); off += 32768;
    int* cntB  = (int*)(ws + off); off += 32768;
    int* n32   = (int*)(ws + off); off += 8192;
    int* listA = (int*)(ws + off); off += 32768;
    int* listB = (int*)(ws + off); off += 32768;
    int* listC = (int*)(ws + off); off += 32768;
    float* zpad = (float*)(ws + off); off += 1024;
    float* pA = (float*)(ws + off); off += (size_t)N_NODES * 32 * 4;
    float* g1 = (float*)(ws + off); off += (size_t)N_NODES * 64 * 4;
    float* g2 = (float*)(ws + off); off += (size_t)N_NODES * 128 * 4;
    unsigned short* xh  = (unsigned short*)(ws + off); off += (size_t)32 * N_NODES * 2;
    unsigned short* xl  = (unsigned short*)(ws + off); off += (size_t)32 * N_NODES * 2;
    unsigned short* uAh = (unsigned short*)(ws + off); off += (size_t)32 * N_NODES * 2;
    unsigned short* uAl = (unsigned short*)(ws + off); off += (size_t)32 * N_NODES * 2;
    unsigned short* uBh = (unsigned short*)(ws + off); off += (size_t)64 * N_NODES * 2;
    unsigned short* uBl = (unsigned short*)(ws + off); off += (size_t)64 * N_NODES * 2;
    const size_t needed = off;

    if (ws_size < needed || n_in != 14 || out_size != N0 * 32) {
        ws_fail_kernel<<<1, 64, 0, stream>>>(out);
        return;
    }

    const int zn4 = (int)((1024 + (size_t)(32 + 64 + 128) * N_NODES * 4) / 16);

    // 1) prep: counts/lists/flags + n32 + xt + zero [zpad|pA|g1|g2]
    prep_kernel<<<260, 1024, 0, stream>>>(d_in[12], x, tau, n32, cntA, cntB, listA,
                                          listB, listC, flags, xh, xl, (float4*)zpad,
                                          zn4);
    // 2) diffusion partials: pA += L[rows, kslice] @ x
    rows_mmg<0><<<dim3(384, 1, KZ), 256, 0, stream>>>(L, L, xh, xl, listA, flags + 2,
                                                      0, zpad, pA);
    // 3) uA = cntA*(x - tau*pA)
    ep0_kernel<<<1024, 256, 0, stream>>>(x, pA, tau, cntA, uAh, uAl);
    // 4) hop1 partials: g1 += [K0|K1][rows, kslice] @ uA
    rows_mmg<1><<<dim3(256, 2, KZ), 256, 0, stream>>>(K0, K1, uAh, uAl, listB,
                                                      flags + 2, 1, zpad, g1);
    // 5) uB = cntB * g1
    ep1_kernel<<<2048, 256, 0, stream>>>(g1, cntB, uBh, uBl);
    // 6) hop2 partials: g2 += [K0|K1][rows, kslice] @ uB (r12-verified y=0..3 map)
    rows_mmg<2><<<dim3(128, 4, KZ), 256, 0, stream>>>(K0, K1, uBh, uBl, listC,
                                                      flags + 2, 2, zpad, g2);
    // 7) head: z-gather + conv + MLP + canary
    head_kernel<<<1024, 256, 0, stream>>>(g1, g2, n32, d_in[13], Wself, Wneigh, bconv,
                                          W1, b1, W2, b2, flags, out);
}

// Round 20
// 224.070 us; speedup vs baseline: 3.2884x; 1.0152x over previous
//
#include <hip/hip_runtime.h>
#include <hip/hip_bf16.h>

#define N_NODES 8192
#define D_IN 32
#define N3 6144
#define N2 4096
#define N1 2048
#define N0 1024
#define NE 16384
#define KZ 4                     // grid-level k-slices
#define KRANGE (N_NODES / KZ)    // 2048 k per block
#define KWAVE (KRANGE / 4)       // 512 k per wave (4 waves)
#define NSTAGE (KWAVE / 64)      // 8 stages of 64 k

using f32x4 = __attribute__((ext_vector_type(4))) float;
using s16x8 = __attribute__((ext_vector_type(8))) short;

__device__ __forceinline__ short f2bf(float f) {
    union { __hip_bfloat16 b; short s; } u;
    u.b = __float2bfloat16(f);
    return u.s;
}
__device__ __forceinline__ float b2f(short s) {
    unsigned int u = ((unsigned int)(unsigned short)s) << 16;
    float f;
    __builtin_memcpy(&f, &u, 4);
    return f;
}
__device__ __forceinline__ void gload16(const float* g, float* l) {
    __builtin_amdgcn_global_load_lds(
        (const __attribute__((address_space(1))) void*)g,
        (__attribute__((address_space(3))) void*)l, 16, 0, 0);
}

// ---------------------------------------------------------------------------
// prep: the three count/compact passes (r13-verified logic) now run on
// PARALLEL blocks 0/1/2 instead of serially on block 0. Block 0 = pass A
// (cntA/listA/flags[2], n32 write, range+tau flag bits). Block 1 = pass B.
// Block 2 = pass C. Blocks 3..66 = x split-transpose; blocks 3..261 zero
// the [zpad|pA|g1|g2] region.
// ---------------------------------------------------------------------------
__global__ __launch_bounds__(1024) void prep_kernel(
    const void* __restrict__ nraw, const float* __restrict__ x,
    const float* __restrict__ tau_p, int* __restrict__ n32,
    int* __restrict__ cntA, int* __restrict__ cntB,
    int* __restrict__ listA, int* __restrict__ listB, int* __restrict__ listC,
    int* __restrict__ flags,
    unsigned short* __restrict__ xh, unsigned short* __restrict__ xl,
    float4* __restrict__ zbase, int zn4) {
    __shared__ int lcnt[N_NODES];
    __shared__ float tile[128][33];
    __shared__ int lnum, lfl;
    const int b = blockIdx.x, t = threadIdx.x;
    const int* ni = (const int*)nraw;
    const long long* nl = (const long long*)nraw;

    if (b < 3) {
        bool n64 = true;
#pragma unroll
        for (int j = 0; j < 8; ++j) {
            long long a = nl[j];
            if (a < 0 || a >= N_NODES) n64 = false;
        }
        if (t == 0) { lnum = 0; lfl = 0; }
        for (int i = t; i < N_NODES; i += 1024) lcnt[i] = 0;
        __syncthreads();
        if (b == 0) {
            // pass A: all 6144 (+ n32[0..2048), + range flag)
            for (int j = t; j < N3; j += 1024) {
                long long v = n64 ? nl[j] : (long long)ni[j];
                if (v < 0 || v >= N_NODES) { atomicOr(&lfl, 2); v = 0; }
                if (j < N1) n32[j] = (int)v;
                atomicAdd(&lcnt[(int)v], 1);
            }
            __syncthreads();
            for (int c = t; c < N_NODES; c += 1024) {
                int cv = lcnt[c];
                cntA[c] = cv;
                if (cv) listA[atomicAdd(&lnum, 1)] = c;
            }
            __syncthreads();
            if (t == 0) {
                flags[2] = lnum;
                int f = lfl;
                if (fabsf(tau_p[0] - 0.1f) > 1e-6f) f |= 32;
                flags[0] = f;
            }
        } else if (b == 1) {
            // pass B: first 4096
            for (int j = t; j < N2; j += 1024) {
                long long v = n64 ? nl[j] : (long long)ni[j];
                v = (v < 0 || v >= N_NODES) ? 0 : v;
                atomicAdd(&lcnt[(int)v], 1);
            }
            __syncthreads();
            for (int c = t; c < N_NODES; c += 1024) {
                int cv = lcnt[c];
                cntB[c] = cv;
                if (cv) listB[atomicAdd(&lnum, 1)] = c;
            }
            __syncthreads();
            if (t == 0) flags[3] = lnum;
        } else {
            // pass C: first 2048
            for (int j = t; j < N1; j += 1024) {
                long long v = n64 ? nl[j] : (long long)ni[j];
                v = (v < 0 || v >= N_NODES) ? 0 : v;
                atomicAdd(&lcnt[(int)v], 1);
            }
            __syncthreads();
            for (int c = t; c < N_NODES; c += 1024) {
                if (lcnt[c]) listC[atomicAdd(&lnum, 1)] = c;
            }
            __syncthreads();
            if (t == 0) flags[4] = lnum;
        }
    } else {
        if (b <= 66) {
            const int c0 = (b - 3) * 128;
            const int d = t & 31, cc = t >> 5;
#pragma unroll
            for (int i = 0; i < 4; ++i)
                tile[cc + 32 * i][d] = x[(size_t)(c0 + cc + 32 * i) * D_IN + d];
            __syncthreads();
#pragma unroll
            for (int i = 0; i < 4; ++i) {
                int idx = t + 1024 * i;
                int dd = idx >> 7;
                int jj = idx & 127;
                float v = tile[jj][dd];
                short h = f2bf(v);
                xh[(size_t)dd * N_NODES + c0 + jj] = (unsigned short)h;
                xl[(size_t)dd * N_NODES + c0 + jj] = (unsigned short)f2bf(v - b2f(h));
            }
        }
        float4 zz = {0.f, 0.f, 0.f, 0.f};
        for (int i = (b - 3) * 1024 + t; i < zn4; i += 259 * 1024) zbase[i] = zz;
    }
}

// ---------------------------------------------------------------------------
// mm tile body (r19-verified, verbatim): async-LDS A double buffer with
// counted vmcnt(4) + B register double buffer; split-bf16 compensated MFMA;
// fp32 atomicAdd partials; reduction buffer aliases tileA.
// ---------------------------------------------------------------------------
template <int MODE>
__device__ __forceinline__ void mm_tile_body(
    const float* __restrict__ Km0, const float* __restrict__ Km1,
    const unsigned short* __restrict__ Bhi, const unsigned short* __restrict__ Blo,
    const int* __restrict__ list, int nrows, int tix, int y, int z,
    const float* __restrict__ zpad, float* __restrict__ outf,
    float* tileA, int* rows_s) {
    constexpr int NF = 2;
    constexpr int NCTOT = (MODE == 0) ? 32 : ((MODE == 1) ? 64 : 128);
    const int c0 = tix * 16;
    const int tid = threadIdx.x;
    const int lane = tid & 63;
    const int wid = tid >> 6;
    const int row = lane & 15;
    const int kg = lane >> 4;

    __syncthreads();
    if (tid < 16) rows_s[tid] = (c0 + tid < nrows) ? list[c0 + tid] : -1;
    __syncthreads();

    const float* Km;
    int boff, zoff;
    if constexpr (MODE == 2) {
        Km = (y >> 1) ? Km1 : Km0;
        boff = (y & 1) * 32;
        zoff = y * 32;
    } else if constexpr (MODE == 1) {
        Km = y ? Km1 : Km0;
        boff = 0;
        zoff = y * 32;
    } else {
        Km = Km0;
        boff = 0;
        zoff = 0;
    }

    const unsigned short* bph[NF];
    const unsigned short* bpl[NF];
    const int kwb = z * KRANGE + wid * KWAVE;
#pragma unroll
    for (int n = 0; n < NF; ++n) {
        size_t boffs = (size_t)(boff + n * 16 + row) * N_NODES + kwb + kg * 8;
        bph[n] = Bhi + boffs;
        bpl[n] = Blo + boffs;
    }

    f32x4 acc[NF];
#pragma unroll
    for (int n = 0; n < NF; ++n) acc[n] = (f32x4){0.f, 0.f, 0.f, 0.f};

    float* twave = tileA + wid * 2048;    // [2][1024] per wave
    const int srow = lane >> 4;
    const int schk = lane & 15;
#define ISSUE(buf, kofs)                                                       \
    {                                                                          \
        _Pragma("unroll") for (int i = 0; i < 4; ++i) {                        \
            int r = i * 4 + srow;                                              \
            int crw = rows_s[r];                                               \
            int sc = schk ^ (r & 15);                                          \
            const float* gp = (crw >= 0)                                       \
                                  ? Km + (size_t)crw * N_NODES + (kofs) + sc * 4 \
                                  : zpad;                                      \
            gload16(gp, twave + (buf) * 1024 + i * 256);                       \
        }                                                                      \
    }
    s16x8 bhr[2][2][NF], blr[2][2][NF];   // [parity][h][n]
#define LOADB(pb, bo)                                                          \
    {                                                                          \
        _Pragma("unroll") for (int h = 0; h < 2; ++h)                          \
            _Pragma("unroll") for (int n = 0; n < NF; ++n) {                   \
                bhr[pb][h][n] = *(const s16x8*)(bph[n] + (bo) + h * 32);       \
                blr[pb][h][n] = *(const s16x8*)(bpl[n] + (bo) + h * 32);       \
            }                                                                  \
    }

    ISSUE(0, kwb);
    LOADB(0, 0);
#pragma unroll
    for (int st = 0; st < NSTAGE; ++st) {
        const int buf = st & 1;
        const int pb = st & 1;
        if (st + 1 < NSTAGE) {
            ISSUE(buf ^ 1, kwb + (st + 1) * 64);
            asm volatile("s_waitcnt vmcnt(4)" ::: "memory");
            __builtin_amdgcn_sched_barrier(0);
            LOADB(pb ^ 1, (st + 1) * 64);      // next-stage B, hides under MFMA
            __builtin_amdgcn_sched_barrier(0);
        } else {
            asm volatile("s_waitcnt vmcnt(0)" ::: "memory");
            __builtin_amdgcn_sched_barrier(0);
        }
        const float* tb = twave + buf * 1024;
#pragma unroll
        for (int h = 0; h < 2; ++h) {
            const int ks = h * 32;
            int c0i = (kg * 8 + ks) >> 2;
            float4 a0 = *(const float4*)&tb[row * 64 + ((c0i ^ (row & 15)) << 2)];
            float4 a1 = *(const float4*)&tb[row * 64 + (((c0i + 1) ^ (row & 15)) << 2)];
            float av[8] = {a0.x, a0.y, a0.z, a0.w, a1.x, a1.y, a1.z, a1.w};
            s16x8 ah, al;
#pragma unroll
            for (int i = 0; i < 8; ++i) {
                short hh = f2bf(av[i]);
                ah[i] = hh;
                al[i] = f2bf(av[i] - b2f(hh));
            }
#pragma unroll
            for (int n = 0; n < NF; ++n) {
                acc[n] = __builtin_amdgcn_mfma_f32_16x16x32_bf16(al, bhr[pb][h][n], acc[n], 0, 0, 0);
                acc[n] = __builtin_amdgcn_mfma_f32_16x16x32_bf16(ah, blr[pb][h][n], acc[n], 0, 0, 0);
                acc[n] = __builtin_amdgcn_mfma_f32_16x16x32_bf16(ah, bhr[pb][h][n], acc[n], 0, 0, 0);
            }
        }
        __builtin_amdgcn_sched_barrier(0);
    }
#undef ISSUE
#undef LOADB

    __syncthreads();
    float* redb = tileA;
#pragma unroll
    for (int n = 0; n < NF; ++n)
#pragma unroll
        for (int r = 0; r < 4; ++r)
            redb[wid * (256 * NF) + (kg * 4 + r) * (16 * NF) + (n * 16 + row)] =
                acc[n][r];
    __syncthreads();

    for (int e = tid; e < 256 * NF; e += 256) {
        float s = redb[e] + redb[256 * NF + e] + redb[2 * 256 * NF + e] +
                  redb[3 * 256 * NF + e];
        int orow = e / (16 * NF);
        int ocol = e % (16 * NF);
        int cc = rows_s[orow];
        if (cc >= 0) atomicAdd(&outf[(size_t)cc * NCTOT + zoff + ocol], s);
    }
}

// epilogue element ops (r15-verified math)
__device__ __forceinline__ void ep0_elem(int idx, const float* x, const float* pA,
                                         const float* tau_p, const int* cntA,
                                         unsigned short* uAh, unsigned short* uAl) {
    int d = idx >> 13, c = idx & (N_NODES - 1);
    float u = (float)cntA[c] * (x[(size_t)c * D_IN + d] - tau_p[0] * pA[(size_t)c * 32 + d]);
    short h = f2bf(u);
    uAh[idx] = (unsigned short)h;
    uAl[idx] = (unsigned short)f2bf(u - b2f(h));
}
__device__ __forceinline__ void ep1_elem(int idx, const float* g1, const int* cntB,
                                         unsigned short* uBh, unsigned short* uBl) {
    int d = idx >> 13, c = idx & (N_NODES - 1);
    float u = (float)cntB[c] * g1[(size_t)c * 64 + d];
    short h = f2bf(u);
    uBh[idx] = (unsigned short)h;
    uBl[idx] = (unsigned short)f2bf(u - b2f(h));
}

// ---------------------------------------------------------------------------
// standalone kernels
// ---------------------------------------------------------------------------
template <int MODE>
__global__ __launch_bounds__(256, 4) void rows_mmg(
    const float* __restrict__ Km0, const float* __restrict__ Km1,
    const unsigned short* __restrict__ Bhi, const unsigned short* __restrict__ Blo,
    const int* __restrict__ list, const int* __restrict__ nptr, int nidx,
    const float* __restrict__ zpad, float* __restrict__ outf) {
    __shared__ float tileA[4 * 2 * 1024];   // 32 KB (k-loop A dbuf, then red)
    __shared__ int rows_s[16];
    int nrows = nptr[nidx];
    if ((int)blockIdx.x * 16 >= nrows) return;
    mm_tile_body<MODE>(Km0, Km1, Bhi, Blo, list, nrows, blockIdx.x, blockIdx.y,
                       blockIdx.z, zpad, outf, tileA, rows_s);
}

__global__ void ep0_kernel(const float* __restrict__ x, const float* __restrict__ pA,
                           const float* __restrict__ tau_p, const int* __restrict__ cntA,
                           unsigned short* __restrict__ uAh, unsigned short* __restrict__ uAl) {
    int idx = blockIdx.x * 256 + threadIdx.x;
    if (idx < N_NODES * 32) ep0_elem(idx, x, pA, tau_p, cntA, uAh, uAl);
}
__global__ void ep1_kernel(const float* __restrict__ g1, const int* __restrict__ cntB,
                           unsigned short* __restrict__ uBh, unsigned short* __restrict__ uBl) {
    int idx = blockIdx.x * 256 + threadIdx.x;
    if (idx < N_NODES * 64) ep1_elem(idx, g1, cntB, uBh, uBl);
}

// head (r15/r17-verified): z-gather inlined + SAGE conv + MLP + canary
__global__ void head_kernel(const float* __restrict__ g1, const float* __restrict__ g2,
                            const int* __restrict__ n32, const void* __restrict__ eraw,
                            const float* __restrict__ Wself, const float* __restrict__ Wneigh,
                            const float* __restrict__ bconv, const float* __restrict__ W1,
                            const float* __restrict__ b1, const float* __restrict__ W2,
                            const float* __restrict__ b2, const int* __restrict__ flags,
                            float* __restrict__ out) {
    __shared__ float zs[192], za[192], hc[128], hm[64];
    __shared__ int csrc[16];
    int t = threadIdx.x, b = blockIdx.x;
    const int* ei = (const int*)eraw;
    const long long* el = (const long long*)eraw;
    if (t < 16) {
        bool e64 = true;
#pragma unroll
        for (int j = 0; j < 8; ++j) {
            long long a = el[j];
            if (a < 0 || a >= N1) e64 = false;
        }
        long long sv = e64 ? el[b * 16 + t] : (long long)ei[b * 16 + t];
        int si = (sv < 0 || sv >= N1) ? 0 : (int)sv;
        csrc[t] = n32[si];
    }
    __syncthreads();
    if (t < 192) {
        int cb = n32[b];
        zs[t] = (t < 64) ? g1[(size_t)cb * 64 + t] : g2[(size_t)cb * 128 + (t - 64)];
        float s = 0.f;
#pragma unroll
        for (int e = 0; e < 16; ++e) {
            int c = csrc[e];
            s += (t < 64) ? g1[(size_t)c * 64 + t] : g2[(size_t)c * 128 + (t - 64)];
        }
        za[t] = s * (1.0f / 16.0f);
    }
    __syncthreads();
    if (t < 128) {
        float s = bconv[t];
        for (int d = 0; d < 192; ++d)
            s += zs[d] * Wself[d * 128 + t] + za[d] * Wneigh[d * 128 + t];
        hc[t] = s;
    }
    __syncthreads();
    if (t < 64) {
        float s = b1[t];
        for (int h = 0; h < 128; ++h) s += hc[h] * W1[h * 64 + t];
        hm[t] = fmaxf(s, 0.0f);
    }
    __syncthreads();
    if (t < 32) {
        float s = b2[t];
        for (int j = 0; j < 64; ++j) s += hm[j] * W2[j * 32 + t];
        out[(size_t)b * 32 + t] = s;
    }
    __syncthreads();
    if (b == 0 && t == 0) {
        int f = flags[0];
        if (f) out[0] = 100000.0f * (float)f;
    }
}

__global__ void ws_fail_kernel(float* out) {
    if (threadIdx.x == 0 && blockIdx.x == 0) out[0] = 100000.0f;
}

// ---------------------------------------------------------------------------
extern "C" void kernel_launch(void* const* d_in, const int* in_sizes, int n_in,
                              void* d_out, int out_size, void* d_ws, size_t ws_size,
                              hipStream_t stream) {
    const float* x      = (const float*)d_in[0];
    const float* tau    = (const float*)d_in[1];
    const float* L      = (const float*)d_in[2];
    const float* K0     = (const float*)d_in[3];
    const float* K1     = (const float*)d_in[4];
    const float* Wself  = (const float*)d_in[5];
    const float* Wneigh = (const float*)d_in[6];
    const float* bconv  = (const float*)d_in[7];
    const float* W1     = (const float*)d_in[8];
    const float* b1     = (const float*)d_in[9];
    const float* W2     = (const float*)d_in[10];
    const float* b2     = (const float*)d_in[11];
    float* out = (float*)d_out;

    char* ws = (char*)d_ws;
    size_t off = 0;
    int* flags = (int*)(ws + off); off += 256;
    int* cntA  = (int*)(ws + off); off += 32768;
    int* cntB  = (int*)(ws + off); off += 32768;
    int* n32   = (int*)(ws + off); off += 8192;
    int* listA = (int*)(ws + off); off += 32768;
    int* listB = (int*)(ws + off); off += 32768;
    int* listC = (int*)(ws + off); off += 32768;
    float* zpad = (float*)(ws + off); off += 1024;
    float* pA = (float*)(ws + off); off += (size_t)N_NODES * 32 * 4;
    float* g1 = (float*)(ws + off); off += (size_t)N_NODES * 64 * 4;
    float* g2 = (float*)(ws + off); off += (size_t)N_NODES * 128 * 4;
    unsigned short* xh  = (unsigned short*)(ws + off); off += (size_t)32 * N_NODES * 2;
    unsigned short* xl  = (unsigned short*)(ws + off); off += (size_t)32 * N_NODES * 2;
    unsigned short* uAh = (unsigned short*)(ws + off); off += (size_t)32 * N_NODES * 2;
    unsigned short* uAl = (unsigned short*)(ws + off); off += (size_t)32 * N_NODES * 2;
    unsigned short* uBh = (unsigned short*)(ws + off); off += (size_t)64 * N_NODES * 2;
    unsigned short* uBl = (unsigned short*)(ws + off); off += (size_t)64 * N_NODES * 2;
    const size_t needed = off;

    if (ws_size < needed || n_in != 14 || out_size != N0 * 32) {
        ws_fail_kernel<<<1, 64, 0, stream>>>(out);
        return;
    }

    const int zn4 = (int)((1024 + (size_t)(32 + 64 + 128) * N_NODES * 4) / 16);

    // 1) prep: parallel count passes (blocks 0-2) + xt (3-66) + zero (3-261)
    prep_kernel<<<262, 1024, 0, stream>>>(d_in[12], x, tau, n32, cntA, cntB, listA,
                                          listB, listC, flags, xh, xl, (float4*)zpad,
                                          zn4);
    // 2) diffusion partials: pA += L[rows, kslice] @ x
    rows_mmg<0><<<dim3(384, 1, KZ), 256, 0, stream>>>(L, L, xh, xl, listA, flags + 2,
                                                      0, zpad, pA);
    // 3) uA = cntA*(x - tau*pA)
    ep0_kernel<<<1024, 256, 0, stream>>>(x, pA, tau, cntA, uAh, uAl);
    // 4) hop1 partials: g1 += [K0|K1][rows, kslice] @ uA
    rows_mmg<1><<<dim3(256, 2, KZ), 256, 0, stream>>>(K0, K1, uAh, uAl, listB,
                                                      flags + 2, 1, zpad, g1);
    // 5) uB = cntB * g1
    ep1_kernel<<<2048, 256, 0, stream>>>(g1, cntB, uBh, uBl);
    // 6) hop2 partials: g2 += [K0|K1][rows, kslice] @ uB (r12-verified y=0..3 map)
    rows_mmg<2><<<dim3(128, 4, KZ), 256, 0, stream>>>(K0, K1, uBh, uBl, listC,
                                                      flags + 2, 2, zpad, g2);
    // 7) head: z-gather + conv + MLP + canary
    head_kernel<<<1024, 256, 0, stream>>>(g1, g2, n32, d_in[13], Wself, Wneigh, bconv,
                                          W1, b1, W2, b2, flags, out);
}

// Round 21
// 221.119 us; speedup vs baseline: 3.3322x; 1.0133x over previous
//
#include <hip/hip_runtime.h>
#include <hip/hip_bf16.h>

#define N_NODES 8192
#define D_IN 32
#define N3 6144
#define N2 4096
#define N1 2048
#define N0 1024
#define NE 16384
#define KZ 4                     // grid-level k-slices
#define KRANGE (N_NODES / KZ)    // 2048 k per block
#define KWAVE (KRANGE / 4)       // 512 k per wave (4 waves)
#define NSTAGE (KWAVE / 64)      // 8 stages of 64 k

using f32x4 = __attribute__((ext_vector_type(4))) float;
using s16x8 = __attribute__((ext_vector_type(8))) short;

__device__ __forceinline__ short f2bf(float f) {
    union { __hip_bfloat16 b; short s; } u;
    u.b = __float2bfloat16(f);
    return u.s;
}
__device__ __forceinline__ float b2f(short s) {
    unsigned int u = ((unsigned int)(unsigned short)s) << 16;
    float f;
    __builtin_memcpy(&f, &u, 4);
    return f;
}
__device__ __forceinline__ void gload16(const float* g, float* l) {
    __builtin_amdgcn_global_load_lds(
        (const __attribute__((address_space(1))) void*)g,
        (__attribute__((address_space(3))) void*)l, 16, 0, 0);
}

// ---------------------------------------------------------------------------
// prep (r20-verified, verbatim): parallel count/compact passes on blocks
// 0/1/2; blocks 3..66 x split-transpose; blocks 3..261 zero [zpad|pA|g1|g2].
// ---------------------------------------------------------------------------
__global__ __launch_bounds__(1024) void prep_kernel(
    const void* __restrict__ nraw, const float* __restrict__ x,
    const float* __restrict__ tau_p, int* __restrict__ n32,
    int* __restrict__ cntA, int* __restrict__ cntB,
    int* __restrict__ listA, int* __restrict__ listB, int* __restrict__ listC,
    int* __restrict__ flags,
    unsigned short* __restrict__ xh, unsigned short* __restrict__ xl,
    float4* __restrict__ zbase, int zn4) {
    __shared__ int lcnt[N_NODES];
    __shared__ float tile[128][33];
    __shared__ int lnum, lfl;
    const int b = blockIdx.x, t = threadIdx.x;
    const int* ni = (const int*)nraw;
    const long long* nl = (const long long*)nraw;

    if (b < 3) {
        bool n64 = true;
#pragma unroll
        for (int j = 0; j < 8; ++j) {
            long long a = nl[j];
            if (a < 0 || a >= N_NODES) n64 = false;
        }
        if (t == 0) { lnum = 0; lfl = 0; }
        for (int i = t; i < N_NODES; i += 1024) lcnt[i] = 0;
        __syncthreads();
        if (b == 0) {
            for (int j = t; j < N3; j += 1024) {
                long long v = n64 ? nl[j] : (long long)ni[j];
                if (v < 0 || v >= N_NODES) { atomicOr(&lfl, 2); v = 0; }
                if (j < N1) n32[j] = (int)v;
                atomicAdd(&lcnt[(int)v], 1);
            }
            __syncthreads();
            for (int c = t; c < N_NODES; c += 1024) {
                int cv = lcnt[c];
                cntA[c] = cv;
                if (cv) listA[atomicAdd(&lnum, 1)] = c;
            }
            __syncthreads();
            if (t == 0) {
                flags[2] = lnum;
                int f = lfl;
                if (fabsf(tau_p[0] - 0.1f) > 1e-6f) f |= 32;
                flags[0] = f;
            }
        } else if (b == 1) {
            for (int j = t; j < N2; j += 1024) {
                long long v = n64 ? nl[j] : (long long)ni[j];
                v = (v < 0 || v >= N_NODES) ? 0 : v;
                atomicAdd(&lcnt[(int)v], 1);
            }
            __syncthreads();
            for (int c = t; c < N_NODES; c += 1024) {
                int cv = lcnt[c];
                cntB[c] = cv;
                if (cv) listB[atomicAdd(&lnum, 1)] = c;
            }
            __syncthreads();
            if (t == 0) flags[3] = lnum;
        } else {
            for (int j = t; j < N1; j += 1024) {
                long long v = n64 ? nl[j] : (long long)ni[j];
                v = (v < 0 || v >= N_NODES) ? 0 : v;
                atomicAdd(&lcnt[(int)v], 1);
            }
            __syncthreads();
            for (int c = t; c < N_NODES; c += 1024) {
                if (lcnt[c]) listC[atomicAdd(&lnum, 1)] = c;
            }
            __syncthreads();
            if (t == 0) flags[4] = lnum;
        }
    } else {
        if (b <= 66) {
            const int c0 = (b - 3) * 128;
            const int d = t & 31, cc = t >> 5;
#pragma unroll
            for (int i = 0; i < 4; ++i)
                tile[cc + 32 * i][d] = x[(size_t)(c0 + cc + 32 * i) * D_IN + d];
            __syncthreads();
#pragma unroll
            for (int i = 0; i < 4; ++i) {
                int idx = t + 1024 * i;
                int dd = idx >> 7;
                int jj = idx & 127;
                float v = tile[jj][dd];
                short h = f2bf(v);
                xh[(size_t)dd * N_NODES + c0 + jj] = (unsigned short)h;
                xl[(size_t)dd * N_NODES + c0 + jj] = (unsigned short)f2bf(v - b2f(h));
            }
        }
        float4 zz = {0.f, 0.f, 0.f, 0.f};
        for (int i = (b - 3) * 1024 + t; i < zn4; i += 259 * 1024) zbase[i] = zz;
    }
}

// ---------------------------------------------------------------------------
// mm tile body. r20 base MINUS the A-residual term: A is used as plain RNE
// bf16 (ah = f2bf(a)); the stored B hi/lo split still compensates B's
// quantization (2 MFMAs per fragment: ah*bl + ah*bh). Cuts the per-stage A
// split VALU by 2/3 and MFMA count by 1/3. Error: A-quantization adds
// ~0.005 RMS per stage (final max ~0.03 vs 0.074 threshold).
// vmcnt unchanged: queue at wait = A[st](4)+B[st](8)+A[st+1](4) -> vmcnt(4)
// completes A[st]+B[st], leaves the next A-prefetch in flight.
// ---------------------------------------------------------------------------
template <int MODE>
__device__ __forceinline__ void mm_tile_body(
    const float* __restrict__ Km0, const float* __restrict__ Km1,
    const unsigned short* __restrict__ Bhi, const unsigned short* __restrict__ Blo,
    const int* __restrict__ list, int nrows, int tix, int y, int z,
    const float* __restrict__ zpad, float* __restrict__ outf,
    float* tileA, int* rows_s) {
    constexpr int NF = 2;
    constexpr int NCTOT = (MODE == 0) ? 32 : ((MODE == 1) ? 64 : 128);
    const int c0 = tix * 16;
    const int tid = threadIdx.x;
    const int lane = tid & 63;
    const int wid = tid >> 6;
    const int row = lane & 15;
    const int kg = lane >> 4;

    __syncthreads();
    if (tid < 16) rows_s[tid] = (c0 + tid < nrows) ? list[c0 + tid] : -1;
    __syncthreads();

    const float* Km;
    int boff, zoff;
    if constexpr (MODE == 2) {
        Km = (y >> 1) ? Km1 : Km0;
        boff = (y & 1) * 32;
        zoff = y * 32;
    } else if constexpr (MODE == 1) {
        Km = y ? Km1 : Km0;
        boff = 0;
        zoff = y * 32;
    } else {
        Km = Km0;
        boff = 0;
        zoff = 0;
    }

    const unsigned short* bph[NF];
    const unsigned short* bpl[NF];
    const int kwb = z * KRANGE + wid * KWAVE;
#pragma unroll
    for (int n = 0; n < NF; ++n) {
        size_t boffs = (size_t)(boff + n * 16 + row) * N_NODES + kwb + kg * 8;
        bph[n] = Bhi + boffs;
        bpl[n] = Blo + boffs;
    }

    f32x4 acc[NF];
#pragma unroll
    for (int n = 0; n < NF; ++n) acc[n] = (f32x4){0.f, 0.f, 0.f, 0.f};

    float* twave = tileA + wid * 2048;    // [2][1024] per wave
    const int srow = lane >> 4;
    const int schk = lane & 15;
#define ISSUE(buf, kofs)                                                       \
    {                                                                          \
        _Pragma("unroll") for (int i = 0; i < 4; ++i) {                        \
            int r = i * 4 + srow;                                              \
            int crw = rows_s[r];                                               \
            int sc = schk ^ (r & 15);                                          \
            const float* gp = (crw >= 0)                                       \
                                  ? Km + (size_t)crw * N_NODES + (kofs) + sc * 4 \
                                  : zpad;                                      \
            gload16(gp, twave + (buf) * 1024 + i * 256);                       \
        }                                                                      \
    }
    s16x8 bhr[2][2][NF], blr[2][2][NF];   // [parity][h][n]
#define LOADB(pb, bo)                                                          \
    {                                                                          \
        _Pragma("unroll") for (int h = 0; h < 2; ++h)                          \
            _Pragma("unroll") for (int n = 0; n < NF; ++n) {                   \
                bhr[pb][h][n] = *(const s16x8*)(bph[n] + (bo) + h * 32);       \
                blr[pb][h][n] = *(const s16x8*)(bpl[n] + (bo) + h * 32);       \
            }                                                                  \
    }

    ISSUE(0, kwb);
    LOADB(0, 0);
#pragma unroll
    for (int st = 0; st < NSTAGE; ++st) {
        const int buf = st & 1;
        const int pb = st & 1;
        if (st + 1 < NSTAGE) {
            ISSUE(buf ^ 1, kwb + (st + 1) * 64);
            asm volatile("s_waitcnt vmcnt(4)" ::: "memory");
            __builtin_amdgcn_sched_barrier(0);
            LOADB(pb ^ 1, (st + 1) * 64);      // next-stage B, hides under MFMA
            __builtin_amdgcn_sched_barrier(0);
        } else {
            asm volatile("s_waitcnt vmcnt(0)" ::: "memory");
            __builtin_amdgcn_sched_barrier(0);
        }
        const float* tb = twave + buf * 1024;
#pragma unroll
        for (int h = 0; h < 2; ++h) {
            const int ks = h * 32;
            int c0i = (kg * 8 + ks) >> 2;
            float4 a0 = *(const float4*)&tb[row * 64 + ((c0i ^ (row & 15)) << 2)];
            float4 a1 = *(const float4*)&tb[row * 64 + (((c0i + 1) ^ (row & 15)) << 2)];
            float av[8] = {a0.x, a0.y, a0.z, a0.w, a1.x, a1.y, a1.z, a1.w};
            s16x8 ah;
#pragma unroll
            for (int i = 0; i < 8; ++i) ah[i] = f2bf(av[i]);
#pragma unroll
            for (int n = 0; n < NF; ++n) {
                acc[n] = __builtin_amdgcn_mfma_f32_16x16x32_bf16(ah, blr[pb][h][n], acc[n], 0, 0, 0);
                acc[n] = __builtin_amdgcn_mfma_f32_16x16x32_bf16(ah, bhr[pb][h][n], acc[n], 0, 0, 0);
            }
        }
        __builtin_amdgcn_sched_barrier(0);
    }
#undef ISSUE
#undef LOADB

    __syncthreads();
    float* redb = tileA;
#pragma unroll
    for (int n = 0; n < NF; ++n)
#pragma unroll
        for (int r = 0; r < 4; ++r)
            redb[wid * (256 * NF) + (kg * 4 + r) * (16 * NF) + (n * 16 + row)] =
                acc[n][r];
    __syncthreads();

    for (int e = tid; e < 256 * NF; e += 256) {
        float s = redb[e] + redb[256 * NF + e] + redb[2 * 256 * NF + e] +
                  redb[3 * 256 * NF + e];
        int orow = e / (16 * NF);
        int ocol = e % (16 * NF);
        int cc = rows_s[orow];
        if (cc >= 0) atomicAdd(&outf[(size_t)cc * NCTOT + zoff + ocol], s);
    }
}

// epilogue element ops (r15-verified math)
__device__ __forceinline__ void ep0_elem(int idx, const float* x, const float* pA,
                                         const float* tau_p, const int* cntA,
                                         unsigned short* uAh, unsigned short* uAl) {
    int d = idx >> 13, c = idx & (N_NODES - 1);
    float u = (float)cntA[c] * (x[(size_t)c * D_IN + d] - tau_p[0] * pA[(size_t)c * 32 + d]);
    short h = f2bf(u);
    uAh[idx] = (unsigned short)h;
    uAl[idx] = (unsigned short)f2bf(u - b2f(h));
}
__device__ __forceinline__ void ep1_elem(int idx, const float* g1, const int* cntB,
                                         unsigned short* uBh, unsigned short* uBl) {
    int d = idx >> 13, c = idx & (N_NODES - 1);
    float u = (float)cntB[c] * g1[(size_t)c * 64 + d];
    short h = f2bf(u);
    uBh[idx] = (unsigned short)h;
    uBl[idx] = (unsigned short)f2bf(u - b2f(h));
}

// ---------------------------------------------------------------------------
// standalone kernels
// ---------------------------------------------------------------------------
template <int MODE>
__global__ __launch_bounds__(256, 4) void rows_mmg(
    const float* __restrict__ Km0, const float* __restrict__ Km1,
    const unsigned short* __restrict__ Bhi, const unsigned short* __restrict__ Blo,
    const int* __restrict__ list, const int* __restrict__ nptr, int nidx,
    const float* __restrict__ zpad, float* __restrict__ outf) {
    __shared__ float tileA[4 * 2 * 1024];   // 32 KB (k-loop A dbuf, then red)
    __shared__ int rows_s[16];
    int nrows = nptr[nidx];
    if ((int)blockIdx.x * 16 >= nrows) return;
    mm_tile_body<MODE>(Km0, Km1, Bhi, Blo, list, nrows, blockIdx.x, blockIdx.y,
                       blockIdx.z, zpad, outf, tileA, rows_s);
}

__global__ void ep0_kernel(const float* __restrict__ x, const float* __restrict__ pA,
                           const float* __restrict__ tau_p, const int* __restrict__ cntA,
                           unsigned short* __restrict__ uAh, unsigned short* __restrict__ uAl) {
    int idx = blockIdx.x * 256 + threadIdx.x;
    if (idx < N_NODES * 32) ep0_elem(idx, x, pA, tau_p, cntA, uAh, uAl);
}
__global__ void ep1_kernel(const float* __restrict__ g1, const int* __restrict__ cntB,
                           unsigned short* __restrict__ uBh, unsigned short* __restrict__ uBl) {
    int idx = blockIdx.x * 256 + threadIdx.x;
    if (idx < N_NODES * 64) ep1_elem(idx, g1, cntB, uBh, uBl);
}

// head (r15/r17-verified): z-gather inlined + SAGE conv + MLP + canary
__global__ void head_kernel(const float* __restrict__ g1, const float* __restrict__ g2,
                            const int* __restrict__ n32, const void* __restrict__ eraw,
                            const float* __restrict__ Wself, const float* __restrict__ Wneigh,
                            const float* __restrict__ bconv, const float* __restrict__ W1,
                            const float* __restrict__ b1, const float* __restrict__ W2,
                            const float* __restrict__ b2, const int* __restrict__ flags,
                            float* __restrict__ out) {
    __shared__ float zs[192], za[192], hc[128], hm[64];
    __shared__ int csrc[16];
    int t = threadIdx.x, b = blockIdx.x;
    const int* ei = (const int*)eraw;
    const long long* el = (const long long*)eraw;
    if (t < 16) {
        bool e64 = true;
#pragma unroll
        for (int j = 0; j < 8; ++j) {
            long long a = el[j];
            if (a < 0 || a >= N1) e64 = false;
        }
        long long sv = e64 ? el[b * 16 + t] : (long long)ei[b * 16 + t];
        int si = (sv < 0 || sv >= N1) ? 0 : (int)sv;
        csrc[t] = n32[si];
    }
    __syncthreads();
    if (t < 192) {
        int cb = n32[b];
        zs[t] = (t < 64) ? g1[(size_t)cb * 64 + t] : g2[(size_t)cb * 128 + (t - 64)];
        float s = 0.f;
#pragma unroll
        for (int e = 0; e < 16; ++e) {
            int c = csrc[e];
            s += (t < 64) ? g1[(size_t)c * 64 + t] : g2[(size_t)c * 128 + (t - 64)];
        }
        za[t] = s * (1.0f / 16.0f);
    }
    __syncthreads();
    if (t < 128) {
        float s = bconv[t];
        for (int d = 0; d < 192; ++d)
            s += zs[d] * Wself[d * 128 + t] + za[d] * Wneigh[d * 128 + t];
        hc[t] = s;
    }
    __syncthreads();
    if (t < 64) {
        float s = b1[t];
        for (int h = 0; h < 128; ++h) s += hc[h] * W1[h * 64 + t];
        hm[t] = fmaxf(s, 0.0f);
    }
    __syncthreads();
    if (t < 32) {
        float s = b2[t];
        for (int j = 0; j < 64; ++j) s += hm[j] * W2[j * 32 + t];
        out[(size_t)b * 32 + t] = s;
    }
    __syncthreads();
    if (b == 0 && t == 0) {
        int f = flags[0];
        if (f) out[0] = 100000.0f * (float)f;
    }
}

__global__ void ws_fail_kernel(float* out) {
    if (threadIdx.x == 0 && blockIdx.x == 0) out[0] = 100000.0f;
}

// ---------------------------------------------------------------------------
extern "C" void kernel_launch(void* const* d_in, const int* in_sizes, int n_in,
                              void* d_out, int out_size, void* d_ws, size_t ws_size,
                              hipStream_t stream) {
    const float* x      = (const float*)d_in[0];
    const float* tau    = (const float*)d_in[1];
    const float* L      = (const float*)d_in[2];
    const float* K0     = (const float*)d_in[3];
    const float* K1     = (const float*)d_in[4];
    const float* Wself  = (const float*)d_in[5];
    const float* Wneigh = (const float*)d_in[6];
    const float* bconv  = (const float*)d_in[7];
    const float* W1     = (const float*)d_in[8];
    const float* b1     = (const float*)d_in[9];
    const float* W2     = (const float*)d_in[10];
    const float* b2     = (const float*)d_in[11];
    float* out = (float*)d_out;

    char* ws = (char*)d_ws;
    size_t off = 0;
    int* flags = (int*)(ws + off); off += 256;
    int* cntA  = (int*)(ws + off); off += 32768;
    int* cntB  = (int*)(ws + off); off += 32768;
    int* n32   = (int*)(ws + off); off += 8192;
    int* listA = (int*)(ws + off); off += 32768;
    int* listB = (int*)(ws + off); off += 32768;
    int* listC = (int*)(ws + off); off += 32768;
    float* zpad = (float*)(ws + off); off += 1024;
    float* pA = (float*)(ws + off); off += (size_t)N_NODES * 32 * 4;
    float* g1 = (float*)(ws + off); off += (size_t)N_NODES * 64 * 4;
    float* g2 = (float*)(ws + off); off += (size_t)N_NODES * 128 * 4;
    unsigned short* xh  = (unsigned short*)(ws + off); off += (size_t)32 * N_NODES * 2;
    unsigned short* xl  = (unsigned short*)(ws + off); off += (size_t)32 * N_NODES * 2;
    unsigned short* uAh = (unsigned short*)(ws + off); off += (size_t)32 * N_NODES * 2;
    unsigned short* uAl = (unsigned short*)(ws + off); off += (size_t)32 * N_NODES * 2;
    unsigned short* uBh = (unsigned short*)(ws + off); off += (size_t)64 * N_NODES * 2;
    unsigned short* uBl = (unsigned short*)(ws + off); off += (size_t)64 * N_NODES * 2;
    const size_t needed = off;

    if (ws_size < needed || n_in != 14 || out_size != N0 * 32) {
        ws_fail_kernel<<<1, 64, 0, stream>>>(out);
        return;
    }

    const int zn4 = (int)((1024 + (size_t)(32 + 64 + 128) * N_NODES * 4) / 16);

    // 1) prep: parallel count passes (blocks 0-2) + xt (3-66) + zero (3-261)
    prep_kernel<<<262, 1024, 0, stream>>>(d_in[12], x, tau, n32, cntA, cntB, listA,
                                          listB, listC, flags, xh, xl, (float4*)zpad,
                                          zn4);
    // 2) diffusion partials: pA += L[rows, kslice] @ x
    rows_mmg<0><<<dim3(384, 1, KZ), 256, 0, stream>>>(L, L, xh, xl, listA, flags + 2,
                                                      0, zpad, pA);
    // 3) uA = cntA*(x - tau*pA)
    ep0_kernel<<<1024, 256, 0, stream>>>(x, pA, tau, cntA, uAh, uAl);
    // 4) hop1 partials: g1 += [K0|K1][rows, kslice] @ uA
    rows_mmg<1><<<dim3(256, 2, KZ), 256, 0, stream>>>(K0, K1, uAh, uAl, listB,
                                                      flags + 2, 1, zpad, g1);
    // 5) uB = cntB * g1
    ep1_kernel<<<2048, 256, 0, stream>>>(g1, cntB, uBh, uBl);
    // 6) hop2 partials: g2 += [K0|K1][rows, kslice] @ uB (r12-verified y=0..3 map)
    rows_mmg<2><<<dim3(128, 4, KZ), 256, 0, stream>>>(K0, K1, uBh, uBl, listC,
                                                      flags + 2, 2, zpad, g2);
    // 7) head: z-gather + conv + MLP + canary
    head_kernel<<<1024, 256, 0, stream>>>(g1, g2, n32, d_in[13], Wself, Wneigh, bconv,
                                          W1, b1, W2, b2, flags, out);
}